// Round 11
// baseline (262.309 us; speedup 1.0000x reference)
//
#include <hip/hip_runtime.h>
#include <stdint.h>
#include <algorithm>

#define DIM   384
#define KCLS  64
#define NPIX  50
#define KSAMP 40
#define NANCH 8192      // BS*N
#define NQ    3200      // K*PIXEL_SIZE
#define NTOT  11392     // NANCH + NQ
#define NXC   2560      // K*KSAMP
// TEMP=0.1 -> 1/TEMP=10 ; TEMP/BASE_TEMP = 0.05 ; LAMB = 25

typedef __attribute__((ext_vector_type(8)))  short s16x8;
typedef __attribute__((ext_vector_type(16))) float f32x16;

struct Idx40 { int v[KSAMP]; };

__device__ __forceinline__ float wave_sum64(float v){
  #pragma unroll
  for (int o = 32; o >= 1; o >>= 1) v += __shfl_xor(v, o);
  return v;
}

__device__ __forceinline__ unsigned short f2bf(float x){
  union { float f; uint32_t u; } c; c.f = x;
  uint32_t r = c.u + 0x7FFFu + ((c.u >> 16) & 1u);   // RNE
  if ((c.u & 0x7F800000u) == 0x7F800000u) r = c.u;   // inf/nan passthrough
  return (unsigned short)(r >> 16);
}

__device__ __forceinline__ float bf2f(unsigned short h){
  union { uint32_t u; float f; } c; c.u = ((uint32_t)h) << 16;
  return c.f;
}

__device__ __forceinline__ void split_hl(float x, unsigned short& hi, unsigned short& lo){
  hi = f2bf(x);
  lo = f2bf(x - bf2f(hi));
}

// async global->LDS, 16B per lane; lds base must be wave-uniform
__device__ __forceinline__ void gload16(const unsigned short* g, unsigned short* l){
  __builtin_amdgcn_global_load_lds(
      (const __attribute__((address_space(1))) unsigned int*)g,
      (__attribute__((address_space(3))) unsigned int*)l, 16, 0, 0);
}

// ---- fused prep (float2 vectorized): normalize feats->fNh; off/pq -> CFhi/lo;
//      cc -> cchi/lo; xc gather ----
__global__ __launch_bounds__(256) void norm_copy_k(const float* __restrict__ feats,
    const float* __restrict__ off, const float* __restrict__ pq,
    const float* __restrict__ CC,
    unsigned short* __restrict__ fNh,
    unsigned short* __restrict__ CFhi, unsigned short* __restrict__ CFlo,
    unsigned short* __restrict__ cchi, unsigned short* __restrict__ cclo,
    unsigned short* __restrict__ xch, Idx40 idx){
  int row  = blockIdx.x * 4 + (threadIdx.x >> 6);
  int lane = threadIdx.x & 63;
  if (row < 2 * NANCH){
    const float2* src = (const float2*)((row < NANCH) ? feats + (size_t)row * DIM
                                                      : off + (size_t)(row - NANCH) * DIM);
    float2 v[3]; float ss = 0.f;
    #pragma unroll
    for (int e = 0; e < 3; e++){
      v[e] = src[lane + 64 * e];
      ss += v[e].x * v[e].x + v[e].y * v[e].y;
    }
    ss = wave_sum64(ss);
    float inv = 1.f / fmaxf(sqrtf(ss), 1e-12f);
    if (row < NANCH){
      uint32_t* dh = (uint32_t*)(fNh + (size_t)row * DIM);
      #pragma unroll
      for (int e = 0; e < 3; e++)
        dh[lane + 64 * e] = (uint32_t)f2bf(v[e].x * inv) | ((uint32_t)f2bf(v[e].y * inv) << 16);
    } else {
      uint32_t* dhh = (uint32_t*)(CFhi + (size_t)(row - NANCH) * DIM);
      uint32_t* dhl = (uint32_t*)(CFlo + (size_t)(row - NANCH) * DIM);
      #pragma unroll
      for (int e = 0; e < 3; e++){
        unsigned short hx, lx, hy, ly;
        split_hl(v[e].x * inv, hx, lx);
        split_hl(v[e].y * inv, hy, ly);
        dhh[lane + 64 * e] = (uint32_t)hx | ((uint32_t)hy << 16);
        dhl[lane + 64 * e] = (uint32_t)lx | ((uint32_t)ly << 16);
      }
    }
  } else if (row < 2 * NANCH + NQ){
    int q = row - 2 * NANCH;
    const float2* src = (const float2*)(pq + (size_t)q * DIM);
    uint32_t* dhh = (uint32_t*)(CFhi + (size_t)(NANCH + q) * DIM);
    uint32_t* dhl = (uint32_t*)(CFlo + (size_t)(NANCH + q) * DIM);
    #pragma unroll
    for (int e = 0; e < 3; e++){
      float2 v = src[lane + 64 * e];
      unsigned short hx, lx, hy, ly;
      split_hl(v.x, hx, lx);
      split_hl(v.y, hy, ly);
      dhh[lane + 64 * e] = (uint32_t)hx | ((uint32_t)hy << 16);
      dhl[lane + 64 * e] = (uint32_t)lx | ((uint32_t)ly << 16);
    }
  } else if (row < 2 * NANCH + NQ + KCLS){
    int r = row - 2 * NANCH - NQ;
    const float2* src = (const float2*)(CC + (size_t)r * DIM);
    uint32_t* dhh = (uint32_t*)(cchi + (size_t)r * DIM);
    uint32_t* dhl = (uint32_t*)(cclo + (size_t)r * DIM);
    #pragma unroll
    for (int e = 0; e < 3; e++){
      float2 v = src[lane + 64 * e];
      unsigned short hx, lx, hy, ly;
      split_hl(v.x, hx, lx);
      split_hl(v.y, hy, ly);
      dhh[lane + 64 * e] = (uint32_t)hx | ((uint32_t)hy << 16);
      dhl[lane + 64 * e] = (uint32_t)lx | ((uint32_t)ly << 16);
    }
  } else {
    int q = row - 2 * NANCH - NQ - KCLS;      // < NXC
    int c = q / KSAMP, t = q - c * KSAMP;
    const float2* src = (const float2*)(pq + ((size_t)c * NPIX + idx.v[t]) * DIM);
    uint32_t* dst = (uint32_t*)(xch + (size_t)q * DIM);
    #pragma unroll
    for (int e = 0; e < 3; e++){
      float2 v = src[lane + 64 * e];
      dst[lane + 64 * e] = (uint32_t)f2bf(v.x) | ((uint32_t)f2bf(v.y) << 16);
    }
  }
}

// ---- logq = 25 * CF @ CC^T via hi/lo bf16 MFMA (fp32-accurate)
//      + FUSED Sinkhorn row-pass 0 (row-LSE normalize) + col-sum 0 ----
__global__ __launch_bounds__(256) void gemm_logq_mfma_k(
    const unsigned short* __restrict__ Ahi, const unsigned short* __restrict__ Alo,
    const unsigned short* __restrict__ Bhi, const unsigned short* __restrict__ Blo,
    float* __restrict__ logq, float* __restrict__ cs0){
  __shared__ unsigned short lAh[128 * 64], lAl[128 * 64];  // 16 KB each
  __shared__ unsigned short lBh[64 * 64],  lBl[64 * 64];   // 8 KB each
  __shared__ float red[4][64];
  int t = threadIdx.x;
  int lane = t & 63, w = t >> 6;
  int l31 = lane & 31, half = lane >> 5;
  int i0 = blockIdx.x * 128;

  int rA = w * 32 + l31;
  int swA = ((rA & 7) << 4);
  int rB0 = l31, rB1 = 32 + l31;
  int swB = ((l31 & 7) << 4);

  f32x16 acc0, acc1;
  #pragma unroll
  for (int r = 0; r < 16; r++){ acc0[r] = 0.f; acc1[r] = 0.f; }

  for (int kc = 0; kc < 6; kc++){
    __syncthreads();
    #pragma unroll
    for (int p = 0; p < 4; p++){
      int c = t + p * 256;
      int row = c >> 3, col = c & 7;
      int sw = ((col << 4) ^ ((row & 7) << 4));
      *(s16x8*)((char*)lAh + row * 128 + sw) =
          *(const s16x8*)(Ahi + (size_t)(i0 + row) * DIM + kc * 64 + col * 8);
      *(s16x8*)((char*)lAl + row * 128 + sw) =
          *(const s16x8*)(Alo + (size_t)(i0 + row) * DIM + kc * 64 + col * 8);
    }
    #pragma unroll
    for (int p = 0; p < 2; p++){
      int c = t + p * 256;
      int row = c >> 3, col = c & 7;
      int sw = ((col << 4) ^ ((row & 7) << 4));
      *(s16x8*)((char*)lBh + row * 128 + sw) =
          *(const s16x8*)(Bhi + (size_t)row * DIM + kc * 64 + col * 8);
      *(s16x8*)((char*)lBl + row * 128 + sw) =
          *(const s16x8*)(Blo + (size_t)row * DIM + kc * 64 + col * 8);
    }
    __syncthreads();
    #pragma unroll
    for (int kk = 0; kk < 4; kk++){
      int kb = kk * 32 + half * 16;
      s16x8 fah  = *(const s16x8*)((char*)lAh + rA * 128 + (kb ^ swA));
      s16x8 fal  = *(const s16x8*)((char*)lAl + rA * 128 + (kb ^ swA));
      s16x8 fb0h = *(const s16x8*)((char*)lBh + rB0 * 128 + (kb ^ swB));
      s16x8 fb0l = *(const s16x8*)((char*)lBl + rB0 * 128 + (kb ^ swB));
      s16x8 fb1h = *(const s16x8*)((char*)lBh + rB1 * 128 + (kb ^ swB));
      s16x8 fb1l = *(const s16x8*)((char*)lBl + rB1 * 128 + (kb ^ swB));
      acc0 = __builtin_amdgcn_mfma_f32_32x32x16_bf16(fah, fb0h, acc0, 0, 0, 0);
      acc0 = __builtin_amdgcn_mfma_f32_32x32x16_bf16(fah, fb0l, acc0, 0, 0, 0);
      acc0 = __builtin_amdgcn_mfma_f32_32x32x16_bf16(fal, fb0h, acc0, 0, 0, 0);
      acc1 = __builtin_amdgcn_mfma_f32_32x32x16_bf16(fah, fb1h, acc1, 0, 0, 0);
      acc1 = __builtin_amdgcn_mfma_f32_32x32x16_bf16(fah, fb1l, acc1, 0, 0, 0);
      acc1 = __builtin_amdgcn_mfma_f32_32x32x16_bf16(fal, fb1h, acc1, 0, 0, 0);
    }
  }

  // Each physical row lives entirely in one 32-lane half-group:
  // cols 0..31 in acc0[r] (lane l31 = col), cols 32..63 in acc1[r].
  float colacc0 = 0.f, colacc1 = 0.f;
  #pragma unroll
  for (int r = 0; r < 16; r++){
    float v0 = 25.f * acc0[r];
    float v1 = 25.f * acc1[r];
    float m = fmaxf(v0, v1);
    #pragma unroll
    for (int o = 16; o >= 1; o >>= 1) m = fmaxf(m, __shfl_xor(m, o));
    float e0 = expf(v0 - m), e1 = expf(v1 - m);
    float s = e0 + e1;
    #pragma unroll
    for (int o = 16; o >= 1; o >>= 1) s += __shfl_xor(s, o);
    float ls = m + logf(s);
    int rowp = (r & 3) + 8 * (r >> 2) + 4 * half;
    size_t row = (size_t)(i0 + w * 32 + rowp);
    logq[row * KCLS + l31]      = v0 - ls;
    logq[row * KCLS + 32 + l31] = v1 - ls;
    float inv = 1.f / s;
    colacc0 += e0 * inv;     // exp(row-normalized), col l31
    colacc1 += e1 * inv;     // col 32+l31
  }
  colacc0 += __shfl_xor(colacc0, 32);
  colacc1 += __shfl_xor(colacc1, 32);
  if (half == 0){ red[w][l31] = colacc0; red[w][32 + l31] = colacc1; }
  __syncthreads();
  if (t < 64) atomicAdd(&cs0[t], red[0][t] + red[1][t] + red[2][t] + red[3][t]);
}

// ---- fused Sinkhorn pass: apply prev col-norm, row-LSE normalize, AND
//      accumulate next column sums. 16 rows/block -> NTOT/16 = 712 blocks. ----
__global__ __launch_bounds__(256) void rowcol_k(float* __restrict__ logq,
    const float* __restrict__ csPrev, float* __restrict__ csNext){
  int r0 = blockIdx.x * 16;
  int t = threadIdx.x, lane = t & 63, w = t >> 6;
  float cl = logf(csPrev[lane]);
  float colacc = 0.f;
  #pragma unroll
  for (int r = w; r < 16; r += 4){
    size_t off = (size_t)(r0 + r) * KCLS + lane;
    float v = logq[off] - cl;
    float m = v;
    #pragma unroll
    for (int o = 32; o >= 1; o >>= 1) m = fmaxf(m, __shfl_xor(m, o));
    float e = expf(v - m);
    float s = wave_sum64(e);
    logq[off] = v - (m + logf(s));
    colacc += e / s;                       // == exp(row-normalized value)
  }
  __shared__ float red[4][64];
  red[w][lane] = colacc;
  __syncthreads();
  if (t < 64) atomicAdd(&csNext[t], red[0][t] + red[1][t] + red[2][t] + red[3][t]);
}

// ---- labels = argmax (+ class histogram fused) ----
__global__ __launch_bounds__(256) void argmax_k(const float* __restrict__ logq,
    const float* __restrict__ cs, int* __restrict__ labels, int* __restrict__ cnt){
  __shared__ float clog[KCLS];
  int t = threadIdx.x;
  if (t < KCLS) clog[t] = logf(cs[t]);
  __syncthreads();
  int i = blockIdx.x * 256 + t;
  if (i >= NANCH) return;
  float best = -INFINITY; int bj = 0;
  for (int j = 0; j < KCLS; j++){
    float v = logq[(size_t)i * KCLS + j] - clog[j];
    if (v > best){ best = v; bj = j; }
  }
  labels[i] = bj;
  atomicAdd(&cnt[bj], 1);
}

__global__ void scan_k(const int* cnt, int* offs, int* offw){
  if (threadIdx.x == 0){
    int acc = 0;
    for (int c = 0; c < KCLS; c++){ offs[c] = acc; offw[c] = acc; acc += cnt[c]; }
  }
}

// ---- scatter + permute S,S2 into class-sorted position order ----
__global__ __launch_bounds__(256) void scatter_k(const int* __restrict__ labels,
    int* offw, int* __restrict__ sorted, const float* __restrict__ S,
    const float* __restrict__ S2, float* __restrict__ Sp, float* __restrict__ S2p){
  int i = blockIdx.x * 256 + threadIdx.x;
  if (i >= NANCH) return;
  int p = atomicAdd(&offw[labels[i]], 1);
  sorted[p] = i;
  Sp[p]  = S[i];
  S2p[p] = S2[i];
}

// ---- fNs[p] = fNh[sorted[p]] : class-contiguous feature rows ----
__global__ __launch_bounds__(256) void sortrows_k(const unsigned short* __restrict__ fNh,
    const int* __restrict__ sorted, unsigned short* __restrict__ fNs){
  int p = blockIdx.x * 4 + (threadIdx.x >> 6);     // 4 rows/block
  int lane = threadIdx.x & 63;
  int src = sorted[p];
  const uint32_t* s = (const uint32_t*)(fNh + (size_t)src * DIM);
  uint32_t* d = (uint32_t*)(fNs + (size_t)p * DIM);
  #pragma unroll
  for (int e = 0; e < 3; e++) d[lane + 64 * e] = s[lane + 64 * e];
}

// ---- MFMA row-sums: CYCLIC-balanced triangle, double-buffered (R10, frozen) ----
// Unordered self pair {i,j} <-> (bi, (bi+d)%64), d in [0,32]; d=32 only bi<32.
// grid.y<8: self chunk d0=4y, njt=4 (wrap mod 64). grid.y==8: d=32 singleton
// (bi<32, else exit). grid.y in [9,14): xc chunks of 4 (dst=S2, rows only).
// Off-diagonal self tiles also emit column-sums into S[j-range].
__global__ __launch_bounds__(256) void rowsums2_k(
    const unsigned short* __restrict__ A, const unsigned short* __restrict__ Bxc,
    float* __restrict__ S, float* __restrict__ S2){
  int bi = blockIdx.x, y = blockIdx.y;
  const unsigned short* Bp; float* dst;
  int d0 = 0, bjx0 = 0, njt; bool selfpart;
  if (y < 8){
    selfpart = true; Bp = A; dst = S; d0 = y * 4; njt = 4;
  } else if (y == 8){
    if (bi >= 32) return;
    selfpart = true; Bp = A; dst = S; d0 = 32; njt = 1;
  } else {
    selfpart = false; Bp = Bxc; dst = S2; bjx0 = (y - 9) * 4; njt = 4;
  }

  __shared__ unsigned short lds[2][2][128 * 64];   // [buf][A|B], 64 KB total
  int t = threadIdx.x, lane = t & 63, w = t >> 6;
  int wr = w >> 1, wc = w & 1;
  int l31 = lane & 31, half = lane >> 5;
  int i0 = bi * 128;
  int lrow = lane >> 3, srcslot = (lane & 7) ^ lrow;
  size_t loff = (size_t)lrow * DIM + srcslot * 8;   // per-lane swizzled source offset

  int rA0 = wr * 64 + l31, rA1 = rA0 + 32;
  int rB0 = wc * 64 + l31, rB1 = rB0 + 32;
  int swA = ((rA0 & 7) << 4), swB = ((rB0 & 7) << 4);

  // j column-tile (in rows of Bp) for tile index jt
  auto jcol = [&](int jt) -> int {
    if (selfpart){ int js = bi + d0 + jt; return (js & 63) * 128; }
    return (bjx0 + jt) * 128;
  };

  f32x16 s0, s1, a00, a01, a10, a11;
  #pragma unroll
  for (int r = 0; r < 16; r++){ s0[r] = 0.f; s1[r] = 0.f; }

  // prologue: stage (jt=0, kc=0) into buf 0
  {
    int j0 = jcol(0);
    #pragma unroll
    for (int c = 0; c < 4; c++){
      int chunk = w * 4 + c;
      gload16(A  + (size_t)(i0 + chunk * 8) * DIM + loff, &lds[0][0][chunk * 512]);
      gload16(Bp + (size_t)(j0 + chunk * 8) * DIM + loff, &lds[0][1][chunk * 512]);
    }
  }
  __syncthreads();

  int total = njt * 6;
  int buf = 0;
  for (int s = 0; s < total; s++){
    int jt = s / 6, kc = s - jt * 6;
    if (s + 1 < total){
      int sn = s + 1;
      int jt1 = sn / 6, kc1 = sn - jt1 * 6;
      int j1 = jcol(jt1);
      int nb = buf ^ 1;
      #pragma unroll
      for (int c = 0; c < 4; c++){
        int chunk = w * 4 + c;
        gload16(A  + (size_t)(i0 + chunk * 8) * DIM + kc1 * 64 + loff, &lds[nb][0][chunk * 512]);
        gload16(Bp + (size_t)(j1 + chunk * 8) * DIM + kc1 * 64 + loff, &lds[nb][1][chunk * 512]);
      }
    }
    if (kc == 0){
      #pragma unroll
      for (int r = 0; r < 16; r++){ a00[r] = 0.f; a01[r] = 0.f; a10[r] = 0.f; a11[r] = 0.f; }
    }
    const char* bA = (const char*)&lds[buf][0][0];
    const char* bB = (const char*)&lds[buf][1][0];
    #pragma unroll
    for (int kk = 0; kk < 4; kk++){
      int kb = kk * 32 + half * 16;
      s16x8 fa0 = *(const s16x8*)(bA + rA0 * 128 + (kb ^ swA));
      s16x8 fa1 = *(const s16x8*)(bA + rA1 * 128 + (kb ^ swA));
      s16x8 fb0 = *(const s16x8*)(bB + rB0 * 128 + (kb ^ swB));
      s16x8 fb1 = *(const s16x8*)(bB + rB1 * 128 + (kb ^ swB));
      a00 = __builtin_amdgcn_mfma_f32_32x32x16_bf16(fa0, fb0, a00, 0, 0, 0);
      a01 = __builtin_amdgcn_mfma_f32_32x32x16_bf16(fa0, fb1, a01, 0, 0, 0);
      a10 = __builtin_amdgcn_mfma_f32_32x32x16_bf16(fa1, fb0, a10, 0, 0, 0);
      a11 = __builtin_amdgcn_mfma_f32_32x32x16_bf16(fa1, fb1, a11, 0, 0, 0);
    }
    if (kc == 5){
      int j0 = jcol(jt);
      bool docol = selfpart && (d0 + jt != 0);
      float c0 = 0.f, c1 = 0.f;
      #pragma unroll
      for (int r = 0; r < 16; r++){
        float e00 = __expf(fmaf(a00[r], 10.f, -10.f));
        float e01 = __expf(fmaf(a01[r], 10.f, -10.f));
        float e10 = __expf(fmaf(a10[r], 10.f, -10.f));
        float e11 = __expf(fmaf(a11[r], 10.f, -10.f));
        s0[r] += e00 + e01;
        s1[r] += e10 + e11;
        c0 += e00 + e10;     // column wc*64 + l31
        c1 += e01 + e11;     // column wc*64 + 32 + l31
      }
      if (docol){
        c0 += __shfl_xor(c0, 32);
        c1 += __shfl_xor(c1, 32);
        if (half == 0){
          atomicAdd(&dst[j0 + wc * 64 + l31], c0);
          atomicAdd(&dst[j0 + wc * 64 + 32 + l31], c1);
        }
      }
    }
    __syncthreads();    // drains vmcnt(0): next buffer ready; all waves done reading buf
    buf ^= 1;
  }

  #pragma unroll
  for (int o = 1; o < 32; o <<= 1){
    #pragma unroll
    for (int r = 0; r < 16; r++){
      s0[r] += __shfl_xor(s0[r], o);
      s1[r] += __shfl_xor(s1[r], o);
    }
  }
  if (l31 == 0){
    #pragma unroll
    for (int r = 0; r < 16; r++){
      int rowp = (r & 3) + 8 * (r >> 2) + 4 * half;
      atomicAdd(&dst[i0 + wr * 64 + rowp], s0[r]);
      atomicAdd(&dst[i0 + wr * 64 + 32 + rowp], s1[r]);
    }
  }
}

// ---- per-class positive numerators, class-sorted rows, position-indexed outputs ----
__device__ __forceinline__ void gram2(const s16x8* afr,
    const unsigned short* b0, const unsigned short* b1, f32x16& acc0, f32x16& acc1){
  #pragma unroll
  for (int ks = 0; ks < 24; ks++){
    s16x8 v0 = *(const s16x8*)(b0 + ks * 16);
    s16x8 v1 = *(const s16x8*)(b1 + ks * 16);
    acc0 = __builtin_amdgcn_mfma_f32_32x32x16_bf16(afr[ks], v0, acc0, 0, 0, 0);
    acc1 = __builtin_amdgcn_mfma_f32_32x32x16_bf16(afr[ks], v1, acc1, 0, 0, 0);
  }
}

__global__ __launch_bounds__(64) void classpair_k(
    const unsigned short* __restrict__ fNs, const unsigned short* __restrict__ xch,
    const int* __restrict__ offs, const int* __restrict__ cnt,
    const float* __restrict__ S, const float* __restrict__ S2,
    float* __restrict__ num2A, float* __restrict__ mlppA, float* __restrict__ validA){
  int c = blockIdx.x;
  int n = cnt[c], o0 = offs[c];
  if (n == 0) return;
  int lane = threadIdx.x;
  int l31 = lane & 31, half = lane >> 5;
  int ntiles = (n + 31) >> 5;

  for (int rt = blockIdx.y; rt < ntiles; rt += gridDim.y){
    int rpos = rt * 32 + l31;
    const unsigned short* arow = fNs + (size_t)(o0 + (rpos < n ? rpos : 0)) * DIM + half * 8;
    s16x8 afr[24];
    #pragma unroll
    for (int ks = 0; ks < 24; ks++) afr[ks] = *(const s16x8*)(arow + ks * 16);

    // ===== ppc2 =====
    f32x16 p20, p21;
    #pragma unroll
    for (int r = 0; r < 16; r++){ p20[r] = 0.f; p21[r] = 0.f; }
    {
      int c1 = 32 + l31;
      const unsigned short* b0 = xch + ((size_t)c * KSAMP + l31) * DIM + half * 8;
      const unsigned short* b1 = xch + ((size_t)c * KSAMP + (c1 < KSAMP ? c1 : 0)) * DIM + half * 8;
      gram2(afr, b0, b1, p20, p21);
    }
    f32x16 red;
    #pragma unroll
    for (int r = 0; r < 16; r++){
      float v0 = expf(fmaf(p20[r], 10.f, -10.f));
      float v1 = (l31 < 8) ? expf(fmaf(p21[r], 10.f, -10.f)) : 0.f;
      red[r] = v0 + v1;
    }
    #pragma unroll
    for (int o = 1; o < 32; o <<= 1)
      #pragma unroll
      for (int r = 0; r < 16; r++) red[r] += __shfl_xor(red[r], o);
    float neg2[16];
    #pragma unroll
    for (int r = 0; r < 16; r++){
      int rowp = (r & 3) + 8 * (r >> 2) + 4 * half;
      int rp = rt * 32 + rowp;
      neg2[r] = (rp < n) ? S2[o0 + rp] - red[r] : 1.f;
    }
    #pragma unroll
    for (int r = 0; r < 16; r++){
      float l0 = fmaf(p20[r], 10.f, -10.f);
      float l1 = fmaf(p21[r], 10.f, -10.f);
      float a = l0 - logf(expf(l0) + neg2[r]);
      float b = (l31 < 8) ? l1 - logf(expf(l1) + neg2[r]) : 0.f;
      red[r] = a + b;
    }
    #pragma unroll
    for (int o = 1; o < 32; o <<= 1)
      #pragma unroll
      for (int r = 0; r < 16; r++) red[r] += __shfl_xor(red[r], o);
    if (l31 == 0){
      #pragma unroll
      for (int r = 0; r < 16; r++){
        int rowp = (r & 3) + 8 * (r >> 2) + 4 * half;
        int rp = rt * 32 + rowp;
        if (rp < n) num2A[o0 + rp] = red[r];
      }
    }

    // ===== ppc =====
    f32x16 pe;
    #pragma unroll
    for (int r = 0; r < 16; r++) pe[r] = 0.f;
    for (int ct = 0; ct < ntiles; ct += 2){
      int cp0 = ct * 32 + l31;
      int cp1 = (ct + 1) * 32 + l31;
      bool has1 = (ct + 1) < ntiles;
      const unsigned short* b0 = fNs + (size_t)(o0 + (cp0 < n ? cp0 : 0)) * DIM + half * 8;
      const unsigned short* b1 = fNs + (size_t)(o0 + (has1 && cp1 < n ? cp1 : 0)) * DIM + half * 8;
      f32x16 a0, a1;
      #pragma unroll
      for (int r = 0; r < 16; r++){ a0[r] = 0.f; a1[r] = 0.f; }
      gram2(afr, b0, b1, a0, a1);
      #pragma unroll
      for (int r = 0; r < 16; r++){
        int rowp = (r & 3) + 8 * (r >> 2) + 4 * half;
        int rp = rt * 32 + rowp;
        if (cp0 < n && cp0 != rp) pe[r] += expf(fmaf(a0[r], 10.f, -10.f));
        if (has1 && cp1 < n && cp1 != rp) pe[r] += expf(fmaf(a1[r], 10.f, -10.f));
      }
    }
    #pragma unroll
    for (int o = 1; o < 32; o <<= 1)
      #pragma unroll
      for (int r = 0; r < 16; r++) pe[r] += __shfl_xor(pe[r], o);
    float neg[16];
    #pragma unroll
    for (int r = 0; r < 16; r++){
      int rowp = (r & 3) + 8 * (r >> 2) + 4 * half;
      int rp = rt * 32 + rowp;
      neg[r] = (rp < n) ? S[o0 + rp] - pe[r] : 1.f;
    }

    f32x16 nm;
    #pragma unroll
    for (int r = 0; r < 16; r++) nm[r] = 0.f;
    for (int ct = 0; ct < ntiles; ct += 2){
      int cp0 = ct * 32 + l31;
      int cp1 = (ct + 1) * 32 + l31;
      bool has1 = (ct + 1) < ntiles;
      const unsigned short* b0 = fNs + (size_t)(o0 + (cp0 < n ? cp0 : 0)) * DIM + half * 8;
      const unsigned short* b1 = fNs + (size_t)(o0 + (has1 && cp1 < n ? cp1 : 0)) * DIM + half * 8;
      f32x16 a0, a1;
      #pragma unroll
      for (int r = 0; r < 16; r++){ a0[r] = 0.f; a1[r] = 0.f; }
      gram2(afr, b0, b1, a0, a1);
      #pragma unroll
      for (int r = 0; r < 16; r++){
        int rowp = (r & 3) + 8 * (r >> 2) + 4 * half;
        int rp = rt * 32 + rowp;
        if (cp0 < n && cp0 != rp){
          float l = fmaf(a0[r], 10.f, -10.f);
          nm[r] += l - logf(expf(l) + neg[r]);
        }
        if (has1 && cp1 < n && cp1 != rp){
          float l = fmaf(a1[r], 10.f, -10.f);
          nm[r] += l - logf(expf(l) + neg[r]);
        }
      }
    }
    #pragma unroll
    for (int o = 1; o < 32; o <<= 1)
      #pragma unroll
      for (int r = 0; r < 16; r++) nm[r] += __shfl_xor(nm[r], o);
    if (l31 == 0){
      #pragma unroll
      for (int r = 0; r < 16; r++){
        int rowp = (r & 3) + 8 * (r >> 2) + 4 * half;
        int rp = rt * 32 + rowp;
        if (rp < n){
          if (n > 1){ mlppA[o0 + rp] = nm[r] / (float)(n - 1); validA[o0 + rp] = 1.f; }
          else      { mlppA[o0 + rp] = 0.f; validA[o0 + rp] = 0.f; }
        }
      }
    }
  }
}

__global__ __launch_bounds__(256) void finalize_k(const float* __restrict__ num2A,
    const float* __restrict__ mlppA, const float* __restrict__ validA,
    float* __restrict__ out){
  int t = threadIdx.x;
  float s2 = 0.f, sm = 0.f, sv = 0.f;
  for (int i = t; i < NANCH; i += 256){ s2 += num2A[i]; sm += mlppA[i]; sv += validA[i]; }
  __shared__ float a2[256], am[256], av[256];
  a2[t] = s2; am[t] = sm; av[t] = sv; __syncthreads();
  for (int o = 128; o >= 1; o >>= 1){
    if (t < o){ a2[t] += a2[t+o]; am[t] += am[t+o]; av[t] += av[t+o]; }
    __syncthreads();
  }
  if (t == 0){
    float loss1 = -0.05f * a2[0] / (40.f * (float)NANCH);
    float loss2 = -0.05f * am[0] / fmaxf(av[0], 1.f);
    out[0] = loss1 + loss2;
  }
}

// ---- host: replicate jax.random.permutation(key(1), 50)[:40] (threefry-2x32) ----
static void tf2x32(uint32_t k0, uint32_t k1, uint32_t x0, uint32_t x1, uint32_t out[2]){
  uint32_t ks[3] = { k0, k1, k0 ^ k1 ^ 0x1BD11BDAu };
  static const int R[2][4] = { {13,15,26,6}, {17,29,16,24} };
  x0 += ks[0]; x1 += ks[1];
  for (int i = 0; i < 5; i++){
    for (int j = 0; j < 4; j++){
      x0 += x1;
      int r = R[i & 1][j];
      x1 = (x1 << r) | (x1 >> (32 - r));
      x1 ^= x0;
    }
    x0 += ks[(i + 1) % 3];
    x1 += ks[(i + 2) % 3] + (uint32_t)(i + 1);
  }
  out[0] = x0; out[1] = x1;
}

static void compute_idx(int idx_out[KSAMP]){
  uint32_t p0[2], p1[2];
  tf2x32(0u, 1u, 0u, 2u, p0);
  tf2x32(0u, 1u, 1u, 3u, p1);
  uint32_t sk0 = p0[1], sk1 = p1[1];        // subkey = keys[1]
  uint32_t bits[NPIX];
  for (int i = 0; i < 25; i++){
    uint32_t o[2];
    tf2x32(sk0, sk1, (uint32_t)i, (uint32_t)(25 + i), o);
    bits[i] = o[0]; bits[25 + i] = o[1];
  }
  int perm[NPIX];
  for (int i = 0; i < NPIX; i++) perm[i] = i;
  std::stable_sort(perm, perm + NPIX, [&](int a, int b){ return bits[a] < bits[b]; });
  for (int i = 0; i < KSAMP; i++) idx_out[i] = perm[i];
}

extern "C" void kernel_launch(void* const* d_in, const int* in_sizes, int n_in,
                              void* d_out, int out_size, void* d_ws, size_t ws_size,
                              hipStream_t stream){
  const float* feats = (const float*)d_in[0];
  const float* off   = (const float*)d_in[1];
  const float* cc    = (const float*)d_in[2];
  const float* pq    = (const float*)d_in[3];
  float* out = (float*)d_out;

  char* ws = (char*)d_ws;
  size_t ofs = 0;
  auto alloc = [&](size_t bytes) -> void* {
    ofs = (ofs + 255) & ~(size_t)255;
    void* p = ws + ofs;
    ofs += bytes;
    return p;
  };
  float* logq   = (float*)alloc((size_t)NTOT * KCLS * 4);
  unsigned short* fNh  = (unsigned short*)alloc((size_t)NANCH * DIM * 2);
  unsigned short* fNs  = (unsigned short*)alloc((size_t)NANCH * DIM * 2);
  unsigned short* CFhi = (unsigned short*)alloc((size_t)NTOT * DIM * 2);
  unsigned short* CFlo = (unsigned short*)alloc((size_t)NTOT * DIM * 2);
  unsigned short* cchi = (unsigned short*)alloc((size_t)KCLS * DIM * 2);
  unsigned short* cclo = (unsigned short*)alloc((size_t)KCLS * DIM * 2);
  unsigned short* xch  = (unsigned short*)alloc((size_t)NXC * DIM * 2);
  // contiguous zero region: S2 | S | cnt | cs0 | cs1 | cs2
  float* S2     = (float*)alloc((2 * NANCH + KCLS + 3 * KCLS) * 4);
  float* S      = S2 + NANCH;
  int*   cnt    = (int*)(S2 + 2 * NANCH);
  float* cs0    = S2 + 2 * NANCH + KCLS;
  float* cs1    = cs0 + KCLS;
  float* cs2    = cs1 + KCLS;
  float* Sp     = (float*)alloc(NANCH * 4);
  float* S2p    = (float*)alloc(NANCH * 4);
  float* num2A  = (float*)alloc(NANCH * 4);
  float* mlppA  = (float*)alloc(NANCH * 4);
  float* validA = (float*)alloc(NANCH * 4);
  int* labels   = (int*)alloc(NANCH * 4);
  int* sorted   = (int*)alloc(NANCH * 4);
  int* offs     = (int*)alloc(KCLS * 4);
  int* offw     = (int*)alloc(KCLS * 4);

  Idx40 idx;
  compute_idx(idx.v);

  hipMemsetAsync(S2, 0, (2 * NANCH + 4 * KCLS) * 4, stream);
  norm_copy_k<<<(2 * NANCH + NQ + KCLS + NXC) / 4, 256, 0, stream>>>(
      feats, off, pq, cc, fNh, CFhi, CFlo, cchi, cclo, xch, idx);
  rowsums2_k<<<dim3(64, 14), 256, 0, stream>>>(fNh, xch, S, S2);
  gemm_logq_mfma_k<<<NTOT / 128, 256, 0, stream>>>(CFhi, CFlo, cchi, cclo, logq, cs0);
  rowcol_k<<<NTOT / 16, 256, 0, stream>>>(logq, cs0, cs1);
  rowcol_k<<<NTOT / 16, 256, 0, stream>>>(logq, cs1, cs2);
  argmax_k<<<NANCH / 256, 256, 0, stream>>>(logq, cs2, labels, cnt);
  scan_k<<<1, 64, 0, stream>>>(cnt, offs, offw);
  scatter_k<<<NANCH / 256, 256, 0, stream>>>(labels, offw, sorted, S, S2, Sp, S2p);
  sortrows_k<<<NANCH / 4, 256, 0, stream>>>(fNh, sorted, fNs);
  classpair_k<<<dim3(KCLS, 8), 64, 0, stream>>>(fNs, xch, offs, cnt, Sp, S2p,
                                                num2A, mlppA, validA);
  finalize_k<<<1, 256, 0, stream>>>(num2A, mlppA, validA, out);
}

// Round 12
// 260.987 us; speedup vs baseline: 1.0051x; 1.0051x over previous
//
#include <hip/hip_runtime.h>
#include <stdint.h>
#include <algorithm>

#define DIM   384
#define KCLS  64
#define NPIX  50
#define KSAMP 40
#define NANCH 8192      // BS*N
#define NQ    3200      // K*PIXEL_SIZE
#define NTOT  11392     // NANCH + NQ
#define NXC   2560      // K*KSAMP
// TEMP=0.1 -> 1/TEMP=10 ; TEMP/BASE_TEMP = 0.05 ; LAMB = 25

typedef __attribute__((ext_vector_type(8)))  short s16x8;
typedef __attribute__((ext_vector_type(16))) float f32x16;

struct Idx40 { int v[KSAMP]; };

__device__ __forceinline__ float wave_sum64(float v){
  #pragma unroll
  for (int o = 32; o >= 1; o >>= 1) v += __shfl_xor(v, o);
  return v;
}

__device__ __forceinline__ unsigned short f2bf(float x){
  union { float f; uint32_t u; } c; c.f = x;
  uint32_t r = c.u + 0x7FFFu + ((c.u >> 16) & 1u);   // RNE
  if ((c.u & 0x7F800000u) == 0x7F800000u) r = c.u;   // inf/nan passthrough
  return (unsigned short)(r >> 16);
}

__device__ __forceinline__ float bf2f(unsigned short h){
  union { uint32_t u; float f; } c; c.u = ((uint32_t)h) << 16;
  return c.f;
}

__device__ __forceinline__ void split_hl(float x, unsigned short& hi, unsigned short& lo){
  hi = f2bf(x);
  lo = f2bf(x - bf2f(hi));
}

// async global->LDS, 16B per lane; lds base must be wave-uniform
__device__ __forceinline__ void gload16(const unsigned short* g, unsigned short* l){
  __builtin_amdgcn_global_load_lds(
      (const __attribute__((address_space(1))) unsigned int*)g,
      (__attribute__((address_space(3))) unsigned int*)l, 16, 0, 0);
}

// ---- fused prep (float2 vectorized): normalize feats->fNh; off/pq -> CFhi/lo;
//      cc -> cchi/lo; xc gather ----
__global__ __launch_bounds__(256) void norm_copy_k(const float* __restrict__ feats,
    const float* __restrict__ off, const float* __restrict__ pq,
    const float* __restrict__ CC,
    unsigned short* __restrict__ fNh,
    unsigned short* __restrict__ CFhi, unsigned short* __restrict__ CFlo,
    unsigned short* __restrict__ cchi, unsigned short* __restrict__ cclo,
    unsigned short* __restrict__ xch, Idx40 idx){
  int row  = blockIdx.x * 4 + (threadIdx.x >> 6);
  int lane = threadIdx.x & 63;
  if (row < 2 * NANCH){
    const float2* src = (const float2*)((row < NANCH) ? feats + (size_t)row * DIM
                                                      : off + (size_t)(row - NANCH) * DIM);
    float2 v[3]; float ss = 0.f;
    #pragma unroll
    for (int e = 0; e < 3; e++){
      v[e] = src[lane + 64 * e];
      ss += v[e].x * v[e].x + v[e].y * v[e].y;
    }
    ss = wave_sum64(ss);
    float inv = 1.f / fmaxf(sqrtf(ss), 1e-12f);
    if (row < NANCH){
      uint32_t* dh = (uint32_t*)(fNh + (size_t)row * DIM);
      #pragma unroll
      for (int e = 0; e < 3; e++)
        dh[lane + 64 * e] = (uint32_t)f2bf(v[e].x * inv) | ((uint32_t)f2bf(v[e].y * inv) << 16);
    } else {
      uint32_t* dhh = (uint32_t*)(CFhi + (size_t)(row - NANCH) * DIM);
      uint32_t* dhl = (uint32_t*)(CFlo + (size_t)(row - NANCH) * DIM);
      #pragma unroll
      for (int e = 0; e < 3; e++){
        unsigned short hx, lx, hy, ly;
        split_hl(v[e].x * inv, hx, lx);
        split_hl(v[e].y * inv, hy, ly);
        dhh[lane + 64 * e] = (uint32_t)hx | ((uint32_t)hy << 16);
        dhl[lane + 64 * e] = (uint32_t)lx | ((uint32_t)ly << 16);
      }
    }
  } else if (row < 2 * NANCH + NQ){
    int q = row - 2 * NANCH;
    const float2* src = (const float2*)(pq + (size_t)q * DIM);
    uint32_t* dhh = (uint32_t*)(CFhi + (size_t)(NANCH + q) * DIM);
    uint32_t* dhl = (uint32_t*)(CFlo + (size_t)(NANCH + q) * DIM);
    #pragma unroll
    for (int e = 0; e < 3; e++){
      float2 v = src[lane + 64 * e];
      unsigned short hx, lx, hy, ly;
      split_hl(v.x, hx, lx);
      split_hl(v.y, hy, ly);
      dhh[lane + 64 * e] = (uint32_t)hx | ((uint32_t)hy << 16);
      dhl[lane + 64 * e] = (uint32_t)lx | ((uint32_t)ly << 16);
    }
  } else if (row < 2 * NANCH + NQ + KCLS){
    int r = row - 2 * NANCH - NQ;
    const float2* src = (const float2*)(CC + (size_t)r * DIM);
    uint32_t* dhh = (uint32_t*)(cchi + (size_t)r * DIM);
    uint32_t* dhl = (uint32_t*)(cclo + (size_t)r * DIM);
    #pragma unroll
    for (int e = 0; e < 3; e++){
      float2 v = src[lane + 64 * e];
      unsigned short hx, lx, hy, ly;
      split_hl(v.x, hx, lx);
      split_hl(v.y, hy, ly);
      dhh[lane + 64 * e] = (uint32_t)hx | ((uint32_t)hy << 16);
      dhl[lane + 64 * e] = (uint32_t)lx | ((uint32_t)ly << 16);
    }
  } else {
    int q = row - 2 * NANCH - NQ - KCLS;      // < NXC
    int c = q / KSAMP, t = q - c * KSAMP;
    const float2* src = (const float2*)(pq + ((size_t)c * NPIX + idx.v[t]) * DIM);
    uint32_t* dst = (uint32_t*)(xch + (size_t)q * DIM);
    #pragma unroll
    for (int e = 0; e < 3; e++){
      float2 v = src[lane + 64 * e];
      dst[lane + 64 * e] = (uint32_t)f2bf(v.x) | ((uint32_t)f2bf(v.y) << 16);
    }
  }
}

// ---- logq = 25 * CF @ CC^T via hi/lo bf16 MFMA (fp32-accurate), plain epilogue ----
__global__ __launch_bounds__(256) void gemm_logq_mfma_k(
    const unsigned short* __restrict__ Ahi, const unsigned short* __restrict__ Alo,
    const unsigned short* __restrict__ Bhi, const unsigned short* __restrict__ Blo,
    float* __restrict__ logq){
  __shared__ unsigned short lAh[128 * 64], lAl[128 * 64];  // 16 KB each
  __shared__ unsigned short lBh[64 * 64],  lBl[64 * 64];   // 8 KB each
  int t = threadIdx.x;
  int lane = t & 63, w = t >> 6;
  int l31 = lane & 31, half = lane >> 5;
  int i0 = blockIdx.x * 128;

  int rA = w * 32 + l31;
  int swA = ((rA & 7) << 4);
  int rB0 = l31, rB1 = 32 + l31;
  int swB = ((l31 & 7) << 4);

  f32x16 acc0, acc1;
  #pragma unroll
  for (int r = 0; r < 16; r++){ acc0[r] = 0.f; acc1[r] = 0.f; }

  for (int kc = 0; kc < 6; kc++){
    __syncthreads();
    #pragma unroll
    for (int p = 0; p < 4; p++){
      int c = t + p * 256;
      int row = c >> 3, col = c & 7;
      int sw = ((col << 4) ^ ((row & 7) << 4));
      *(s16x8*)((char*)lAh + row * 128 + sw) =
          *(const s16x8*)(Ahi + (size_t)(i0 + row) * DIM + kc * 64 + col * 8);
      *(s16x8*)((char*)lAl + row * 128 + sw) =
          *(const s16x8*)(Alo + (size_t)(i0 + row) * DIM + kc * 64 + col * 8);
    }
    #pragma unroll
    for (int p = 0; p < 2; p++){
      int c = t + p * 256;
      int row = c >> 3, col = c & 7;
      int sw = ((col << 4) ^ ((row & 7) << 4));
      *(s16x8*)((char*)lBh + row * 128 + sw) =
          *(const s16x8*)(Bhi + (size_t)row * DIM + kc * 64 + col * 8);
      *(s16x8*)((char*)lBl + row * 128 + sw) =
          *(const s16x8*)(Blo + (size_t)row * DIM + kc * 64 + col * 8);
    }
    __syncthreads();
    #pragma unroll
    for (int kk = 0; kk < 4; kk++){
      int kb = kk * 32 + half * 16;
      s16x8 fah  = *(const s16x8*)((char*)lAh + rA * 128 + (kb ^ swA));
      s16x8 fal  = *(const s16x8*)((char*)lAl + rA * 128 + (kb ^ swA));
      s16x8 fb0h = *(const s16x8*)((char*)lBh + rB0 * 128 + (kb ^ swB));
      s16x8 fb0l = *(const s16x8*)((char*)lBl + rB0 * 128 + (kb ^ swB));
      s16x8 fb1h = *(const s16x8*)((char*)lBh + rB1 * 128 + (kb ^ swB));
      s16x8 fb1l = *(const s16x8*)((char*)lBl + rB1 * 128 + (kb ^ swB));
      acc0 = __builtin_amdgcn_mfma_f32_32x32x16_bf16(fah, fb0h, acc0, 0, 0, 0);
      acc0 = __builtin_amdgcn_mfma_f32_32x32x16_bf16(fah, fb0l, acc0, 0, 0, 0);
      acc0 = __builtin_amdgcn_mfma_f32_32x32x16_bf16(fal, fb0h, acc0, 0, 0, 0);
      acc1 = __builtin_amdgcn_mfma_f32_32x32x16_bf16(fah, fb1h, acc1, 0, 0, 0);
      acc1 = __builtin_amdgcn_mfma_f32_32x32x16_bf16(fah, fb1l, acc1, 0, 0, 0);
      acc1 = __builtin_amdgcn_mfma_f32_32x32x16_bf16(fal, fb1h, acc1, 0, 0, 0);
    }
  }
  #pragma unroll
  for (int r = 0; r < 16; r++){
    int rowp = (r & 3) + 8 * (r >> 2) + 4 * half;
    size_t row = (size_t)(i0 + w * 32 + rowp);
    logq[row * KCLS + l31]      = 25.f * acc0[r];
    logq[row * KCLS + 32 + l31] = 25.f * acc1[r];
  }
}

// ---- fused Sinkhorn pass: apply prev col-norm (opt), row-LSE normalize, AND
//      accumulate next column sums. 16 rows/block -> NTOT/16 = 712 blocks. ----
__global__ __launch_bounds__(256) void rowcol_k(float* __restrict__ logq,
    const float* __restrict__ csPrev, float* __restrict__ csNext, int useCol){
  int r0 = blockIdx.x * 16;
  int t = threadIdx.x, lane = t & 63, w = t >> 6;
  float cl = useCol ? logf(csPrev[lane]) : 0.f;
  float colacc = 0.f;
  #pragma unroll
  for (int r = w; r < 16; r += 4){
    size_t off = (size_t)(r0 + r) * KCLS + lane;
    float v = logq[off] - cl;
    float m = v;
    #pragma unroll
    for (int o = 32; o >= 1; o >>= 1) m = fmaxf(m, __shfl_xor(m, o));
    float e = expf(v - m);
    float s = wave_sum64(e);
    logq[off] = v - (m + logf(s));
    colacc += e / s;                       // == exp(row-normalized value)
  }
  __shared__ float red[4][64];
  red[w][lane] = colacc;
  __syncthreads();
  if (t < 64) atomicAdd(&csNext[t], red[0][t] + red[1][t] + red[2][t] + red[3][t]);
}

// ---- labels = argmax (+ class histogram fused) ----
__global__ __launch_bounds__(256) void argmax_k(const float* __restrict__ logq,
    const float* __restrict__ cs, int* __restrict__ labels, int* __restrict__ cnt){
  __shared__ float clog[KCLS];
  int t = threadIdx.x;
  if (t < KCLS) clog[t] = logf(cs[t]);
  __syncthreads();
  int i = blockIdx.x * 256 + t;
  if (i >= NANCH) return;
  float best = -INFINITY; int bj = 0;
  for (int j = 0; j < KCLS; j++){
    float v = logq[(size_t)i * KCLS + j] - clog[j];
    if (v > best){ best = v; bj = j; }
  }
  labels[i] = bj;
  atomicAdd(&cnt[bj], 1);
}

__global__ void scan_k(const int* cnt, int* offs, int* offw){
  if (threadIdx.x == 0){
    int acc = 0;
    for (int c = 0; c < KCLS; c++){ offs[c] = acc; offw[c] = acc; acc += cnt[c]; }
  }
}

// ---- scatter + permute S,S2 into class-sorted position order ----
__global__ __launch_bounds__(256) void scatter_k(const int* __restrict__ labels,
    int* offw, int* __restrict__ sorted, const float* __restrict__ S,
    const float* __restrict__ S2, float* __restrict__ Sp, float* __restrict__ S2p){
  int i = blockIdx.x * 256 + threadIdx.x;
  if (i >= NANCH) return;
  int p = atomicAdd(&offw[labels[i]], 1);
  sorted[p] = i;
  Sp[p]  = S[i];
  S2p[p] = S2[i];
}

// ---- fNs[p] = fNh[sorted[p]] : class-contiguous feature rows ----
__global__ __launch_bounds__(256) void sortrows_k(const unsigned short* __restrict__ fNh,
    const int* __restrict__ sorted, unsigned short* __restrict__ fNs){
  int p = blockIdx.x * 4 + (threadIdx.x >> 6);     // 4 rows/block
  int lane = threadIdx.x & 63;
  int src = sorted[p];
  const uint32_t* s = (const uint32_t*)(fNh + (size_t)src * DIM);
  uint32_t* d = (uint32_t*)(fNs + (size_t)p * DIM);
  #pragma unroll
  for (int e = 0; e < 3; e++) d[lane + 64 * e] = s[lane + 64 * e];
}

// ---- MFMA row-sums: CYCLIC-balanced triangle, double-buffered (R10, frozen) ----
// Unordered self pair {i,j} <-> (bi, (bi+d)%64), d in [0,32]; d=32 only bi<32.
// grid.y<8: self chunk d0=4y, njt=4 (wrap mod 64). grid.y==8: d=32 singleton
// (bi<32, else exit). grid.y in [9,14): xc chunks of 4 (dst=S2, rows only).
// Off-diagonal self tiles also emit column-sums into S[j-range].
__global__ __launch_bounds__(256) void rowsums2_k(
    const unsigned short* __restrict__ A, const unsigned short* __restrict__ Bxc,
    float* __restrict__ S, float* __restrict__ S2){
  int bi = blockIdx.x, y = blockIdx.y;
  const unsigned short* Bp; float* dst;
  int d0 = 0, bjx0 = 0, njt; bool selfpart;
  if (y < 8){
    selfpart = true; Bp = A; dst = S; d0 = y * 4; njt = 4;
  } else if (y == 8){
    if (bi >= 32) return;
    selfpart = true; Bp = A; dst = S; d0 = 32; njt = 1;
  } else {
    selfpart = false; Bp = Bxc; dst = S2; bjx0 = (y - 9) * 4; njt = 4;
  }

  __shared__ unsigned short lds[2][2][128 * 64];   // [buf][A|B], 64 KB total
  int t = threadIdx.x, lane = t & 63, w = t >> 6;
  int wr = w >> 1, wc = w & 1;
  int l31 = lane & 31, half = lane >> 5;
  int i0 = bi * 128;
  int lrow = lane >> 3, srcslot = (lane & 7) ^ lrow;
  size_t loff = (size_t)lrow * DIM + srcslot * 8;   // per-lane swizzled source offset

  int rA0 = wr * 64 + l31, rA1 = rA0 + 32;
  int rB0 = wc * 64 + l31, rB1 = rB0 + 32;
  int swA = ((rA0 & 7) << 4), swB = ((rB0 & 7) << 4);

  // j column-tile (in rows of Bp) for tile index jt
  auto jcol = [&](int jt) -> int {
    if (selfpart){ int js = bi + d0 + jt; return (js & 63) * 128; }
    return (bjx0 + jt) * 128;
  };

  f32x16 s0, s1, a00, a01, a10, a11;
  #pragma unroll
  for (int r = 0; r < 16; r++){ s0[r] = 0.f; s1[r] = 0.f; }

  // prologue: stage (jt=0, kc=0) into buf 0
  {
    int j0 = jcol(0);
    #pragma unroll
    for (int c = 0; c < 4; c++){
      int chunk = w * 4 + c;
      gload16(A  + (size_t)(i0 + chunk * 8) * DIM + loff, &lds[0][0][chunk * 512]);
      gload16(Bp + (size_t)(j0 + chunk * 8) * DIM + loff, &lds[0][1][chunk * 512]);
    }
  }
  __syncthreads();

  int total = njt * 6;
  int buf = 0;
  for (int s = 0; s < total; s++){
    int jt = s / 6, kc = s - jt * 6;
    if (s + 1 < total){
      int sn = s + 1;
      int jt1 = sn / 6, kc1 = sn - jt1 * 6;
      int j1 = jcol(jt1);
      int nb = buf ^ 1;
      #pragma unroll
      for (int c = 0; c < 4; c++){
        int chunk = w * 4 + c;
        gload16(A  + (size_t)(i0 + chunk * 8) * DIM + kc1 * 64 + loff, &lds[nb][0][chunk * 512]);
        gload16(Bp + (size_t)(j1 + chunk * 8) * DIM + kc1 * 64 + loff, &lds[nb][1][chunk * 512]);
      }
    }
    if (kc == 0){
      #pragma unroll
      for (int r = 0; r < 16; r++){ a00[r] = 0.f; a01[r] = 0.f; a10[r] = 0.f; a11[r] = 0.f; }
    }
    const char* bA = (const char*)&lds[buf][0][0];
    const char* bB = (const char*)&lds[buf][1][0];
    #pragma unroll
    for (int kk = 0; kk < 4; kk++){
      int kb = kk * 32 + half * 16;
      s16x8 fa0 = *(const s16x8*)(bA + rA0 * 128 + (kb ^ swA));
      s16x8 fa1 = *(const s16x8*)(bA + rA1 * 128 + (kb ^ swA));
      s16x8 fb0 = *(const s16x8*)(bB + rB0 * 128 + (kb ^ swB));
      s16x8 fb1 = *(const s16x8*)(bB + rB1 * 128 + (kb ^ swB));
      a00 = __builtin_amdgcn_mfma_f32_32x32x16_bf16(fa0, fb0, a00, 0, 0, 0);
      a01 = __builtin_amdgcn_mfma_f32_32x32x16_bf16(fa0, fb1, a01, 0, 0, 0);
      a10 = __builtin_amdgcn_mfma_f32_32x32x16_bf16(fa1, fb0, a10, 0, 0, 0);
      a11 = __builtin_amdgcn_mfma_f32_32x32x16_bf16(fa1, fb1, a11, 0, 0, 0);
    }
    if (kc == 5){
      int j0 = jcol(jt);
      bool docol = selfpart && (d0 + jt != 0);
      float c0 = 0.f, c1 = 0.f;
      #pragma unroll
      for (int r = 0; r < 16; r++){
        float e00 = __expf(fmaf(a00[r], 10.f, -10.f));
        float e01 = __expf(fmaf(a01[r], 10.f, -10.f));
        float e10 = __expf(fmaf(a10[r], 10.f, -10.f));
        float e11 = __expf(fmaf(a11[r], 10.f, -10.f));
        s0[r] += e00 + e01;
        s1[r] += e10 + e11;
        c0 += e00 + e10;     // column wc*64 + l31
        c1 += e01 + e11;     // column wc*64 + 32 + l31
      }
      if (docol){
        c0 += __shfl_xor(c0, 32);
        c1 += __shfl_xor(c1, 32);
        if (half == 0){
          atomicAdd(&dst[j0 + wc * 64 + l31], c0);
          atomicAdd(&dst[j0 + wc * 64 + 32 + l31], c1);
        }
      }
    }
    __syncthreads();    // drains vmcnt(0): next buffer ready; all waves done reading buf
    buf ^= 1;
  }

  #pragma unroll
  for (int o = 1; o < 32; o <<= 1){
    #pragma unroll
    for (int r = 0; r < 16; r++){
      s0[r] += __shfl_xor(s0[r], o);
      s1[r] += __shfl_xor(s1[r], o);
    }
  }
  if (l31 == 0){
    #pragma unroll
    for (int r = 0; r < 16; r++){
      int rowp = (r & 3) + 8 * (r >> 2) + 4 * half;
      atomicAdd(&dst[i0 + wr * 64 + rowp], s0[r]);
      atomicAdd(&dst[i0 + wr * 64 + 32 + rowp], s1[r]);
    }
  }
}

// ---- per-class positive numerators, class-sorted rows, position-indexed outputs ----
__device__ __forceinline__ void gram2(const s16x8* afr,
    const unsigned short* b0, const unsigned short* b1, f32x16& acc0, f32x16& acc1){
  #pragma unroll
  for (int ks = 0; ks < 24; ks++){
    s16x8 v0 = *(const s16x8*)(b0 + ks * 16);
    s16x8 v1 = *(const s16x8*)(b1 + ks * 16);
    acc0 = __builtin_amdgcn_mfma_f32_32x32x16_bf16(afr[ks], v0, acc0, 0, 0, 0);
    acc1 = __builtin_amdgcn_mfma_f32_32x32x16_bf16(afr[ks], v1, acc1, 0, 0, 0);
  }
}

__global__ __launch_bounds__(64) void classpair_k(
    const unsigned short* __restrict__ fNs, const unsigned short* __restrict__ xch,
    const int* __restrict__ offs, const int* __restrict__ cnt,
    const float* __restrict__ S, const float* __restrict__ S2,
    float* __restrict__ num2A, float* __restrict__ mlppA, float* __restrict__ validA){
  int c = blockIdx.x;
  int n = cnt[c], o0 = offs[c];
  if (n == 0) return;
  int lane = threadIdx.x;
  int l31 = lane & 31, half = lane >> 5;
  int ntiles = (n + 31) >> 5;

  for (int rt = blockIdx.y; rt < ntiles; rt += gridDim.y){
    int rpos = rt * 32 + l31;
    const unsigned short* arow = fNs + (size_t)(o0 + (rpos < n ? rpos : 0)) * DIM + half * 8;
    s16x8 afr[24];
    #pragma unroll
    for (int ks = 0; ks < 24; ks++) afr[ks] = *(const s16x8*)(arow + ks * 16);

    // ===== ppc2 =====
    f32x16 p20, p21;
    #pragma unroll
    for (int r = 0; r < 16; r++){ p20[r] = 0.f; p21[r] = 0.f; }
    {
      int c1 = 32 + l31;
      const unsigned short* b0 = xch + ((size_t)c * KSAMP + l31) * DIM + half * 8;
      const unsigned short* b1 = xch + ((size_t)c * KSAMP + (c1 < KSAMP ? c1 : 0)) * DIM + half * 8;
      gram2(afr, b0, b1, p20, p21);
    }
    f32x16 red;
    #pragma unroll
    for (int r = 0; r < 16; r++){
      float v0 = expf(fmaf(p20[r], 10.f, -10.f));
      float v1 = (l31 < 8) ? expf(fmaf(p21[r], 10.f, -10.f)) : 0.f;
      red[r] = v0 + v1;
    }
    #pragma unroll
    for (int o = 1; o < 32; o <<= 1)
      #pragma unroll
      for (int r = 0; r < 16; r++) red[r] += __shfl_xor(red[r], o);
    float neg2[16];
    #pragma unroll
    for (int r = 0; r < 16; r++){
      int rowp = (r & 3) + 8 * (r >> 2) + 4 * half;
      int rp = rt * 32 + rowp;
      neg2[r] = (rp < n) ? S2[o0 + rp] - red[r] : 1.f;
    }
    #pragma unroll
    for (int r = 0; r < 16; r++){
      float l0 = fmaf(p20[r], 10.f, -10.f);
      float l1 = fmaf(p21[r], 10.f, -10.f);
      float a = l0 - logf(expf(l0) + neg2[r]);
      float b = (l31 < 8) ? l1 - logf(expf(l1) + neg2[r]) : 0.f;
      red[r] = a + b;
    }
    #pragma unroll
    for (int o = 1; o < 32; o <<= 1)
      #pragma unroll
      for (int r = 0; r < 16; r++) red[r] += __shfl_xor(red[r], o);
    if (l31 == 0){
      #pragma unroll
      for (int r = 0; r < 16; r++){
        int rowp = (r & 3) + 8 * (r >> 2) + 4 * half;
        int rp = rt * 32 + rowp;
        if (rp < n) num2A[o0 + rp] = red[r];
      }
    }

    // ===== ppc =====
    f32x16 pe;
    #pragma unroll
    for (int r = 0; r < 16; r++) pe[r] = 0.f;
    for (int ct = 0; ct < ntiles; ct += 2){
      int cp0 = ct * 32 + l31;
      int cp1 = (ct + 1) * 32 + l31;
      bool has1 = (ct + 1) < ntiles;
      const unsigned short* b0 = fNs + (size_t)(o0 + (cp0 < n ? cp0 : 0)) * DIM + half * 8;
      const unsigned short* b1 = fNs + (size_t)(o0 + (has1 && cp1 < n ? cp1 : 0)) * DIM + half * 8;
      f32x16 a0, a1;
      #pragma unroll
      for (int r = 0; r < 16; r++){ a0[r] = 0.f; a1[r] = 0.f; }
      gram2(afr, b0, b1, a0, a1);
      #pragma unroll
      for (int r = 0; r < 16; r++){
        int rowp = (r & 3) + 8 * (r >> 2) + 4 * half;
        int rp = rt * 32 + rowp;
        if (cp0 < n && cp0 != rp) pe[r] += expf(fmaf(a0[r], 10.f, -10.f));
        if (has1 && cp1 < n && cp1 != rp) pe[r] += expf(fmaf(a1[r], 10.f, -10.f));
      }
    }
    #pragma unroll
    for (int o = 1; o < 32; o <<= 1)
      #pragma unroll
      for (int r = 0; r < 16; r++) pe[r] += __shfl_xor(pe[r], o);
    float neg[16];
    #pragma unroll
    for (int r = 0; r < 16; r++){
      int rowp = (r & 3) + 8 * (r >> 2) + 4 * half;
      int rp = rt * 32 + rowp;
      neg[r] = (rp < n) ? S[o0 + rp] - pe[r] : 1.f;
    }

    f32x16 nm;
    #pragma unroll
    for (int r = 0; r < 16; r++) nm[r] = 0.f;
    for (int ct = 0; ct < ntiles; ct += 2){
      int cp0 = ct * 32 + l31;
      int cp1 = (ct + 1) * 32 + l31;
      bool has1 = (ct + 1) < ntiles;
      const unsigned short* b0 = fNs + (size_t)(o0 + (cp0 < n ? cp0 : 0)) * DIM + half * 8;
      const unsigned short* b1 = fNs + (size_t)(o0 + (has1 && cp1 < n ? cp1 : 0)) * DIM + half * 8;
      f32x16 a0, a1;
      #pragma unroll
      for (int r = 0; r < 16; r++){ a0[r] = 0.f; a1[r] = 0.f; }
      gram2(afr, b0, b1, a0, a1);
      #pragma unroll
      for (int r = 0; r < 16; r++){
        int rowp = (r & 3) + 8 * (r >> 2) + 4 * half;
        int rp = rt * 32 + rowp;
        if (cp0 < n && cp0 != rp){
          float l = fmaf(a0[r], 10.f, -10.f);
          nm[r] += l - logf(expf(l) + neg[r]);
        }
        if (has1 && cp1 < n && cp1 != rp){
          float l = fmaf(a1[r], 10.f, -10.f);
          nm[r] += l - logf(expf(l) + neg[r]);
        }
      }
    }
    #pragma unroll
    for (int o = 1; o < 32; o <<= 1)
      #pragma unroll
      for (int r = 0; r < 16; r++) nm[r] += __shfl_xor(nm[r], o);
    if (l31 == 0){
      #pragma unroll
      for (int r = 0; r < 16; r++){
        int rowp = (r & 3) + 8 * (r >> 2) + 4 * half;
        int rp = rt * 32 + rowp;
        if (rp < n){
          if (n > 1){ mlppA[o0 + rp] = nm[r] / (float)(n - 1); validA[o0 + rp] = 1.f; }
          else      { mlppA[o0 + rp] = 0.f; validA[o0 + rp] = 0.f; }
        }
      }
    }
  }
}

__global__ __launch_bounds__(256) void finalize_k(const float* __restrict__ num2A,
    const float* __restrict__ mlppA, const float* __restrict__ validA,
    float* __restrict__ out){
  int t = threadIdx.x;
  float s2 = 0.f, sm = 0.f, sv = 0.f;
  for (int i = t; i < NANCH; i += 256){ s2 += num2A[i]; sm += mlppA[i]; sv += validA[i]; }
  __shared__ float a2[256], am[256], av[256];
  a2[t] = s2; am[t] = sm; av[t] = sv; __syncthreads();
  for (int o = 128; o >= 1; o >>= 1){
    if (t < o){ a2[t] += a2[t+o]; am[t] += am[t+o]; av[t] += av[t+o]; }
    __syncthreads();
  }
  if (t == 0){
    float loss1 = -0.05f * a2[0] / (40.f * (float)NANCH);
    float loss2 = -0.05f * am[0] / fmaxf(av[0], 1.f);
    out[0] = loss1 + loss2;
  }
}

// ---- host: replicate jax.random.permutation(key(1), 50)[:40] (threefry-2x32) ----
static void tf2x32(uint32_t k0, uint32_t k1, uint32_t x0, uint32_t x1, uint32_t out[2]){
  uint32_t ks[3] = { k0, k1, k0 ^ k1 ^ 0x1BD11BDAu };
  static const int R[2][4] = { {13,15,26,6}, {17,29,16,24} };
  x0 += ks[0]; x1 += ks[1];
  for (int i = 0; i < 5; i++){
    for (int j = 0; j < 4; j++){
      x0 += x1;
      int r = R[i & 1][j];
      x1 = (x1 << r) | (x1 >> (32 - r));
      x1 ^= x0;
    }
    x0 += ks[(i + 1) % 3];
    x1 += ks[(i + 2) % 3] + (uint32_t)(i + 1);
  }
  out[0] = x0; out[1] = x1;
}

static void compute_idx(int idx_out[KSAMP]){
  uint32_t p0[2], p1[2];
  tf2x32(0u, 1u, 0u, 2u, p0);
  tf2x32(0u, 1u, 1u, 3u, p1);
  uint32_t sk0 = p0[1], sk1 = p1[1];        // subkey = keys[1]
  uint32_t bits[NPIX];
  for (int i = 0; i < 25; i++){
    uint32_t o[2];
    tf2x32(sk0, sk1, (uint32_t)i, (uint32_t)(25 + i), o);
    bits[i] = o[0]; bits[25 + i] = o[1];
  }
  int perm[NPIX];
  for (int i = 0; i < NPIX; i++) perm[i] = i;
  std::stable_sort(perm, perm + NPIX, [&](int a, int b){ return bits[a] < bits[b]; });
  for (int i = 0; i < KSAMP; i++) idx_out[i] = perm[i];
}

extern "C" void kernel_launch(void* const* d_in, const int* in_sizes, int n_in,
                              void* d_out, int out_size, void* d_ws, size_t ws_size,
                              hipStream_t stream){
  const float* feats = (const float*)d_in[0];
  const float* off   = (const float*)d_in[1];
  const float* cc    = (const float*)d_in[2];
  const float* pq    = (const float*)d_in[3];
  float* out = (float*)d_out;

  char* ws = (char*)d_ws;
  size_t ofs = 0;
  auto alloc = [&](size_t bytes) -> void* {
    ofs = (ofs + 255) & ~(size_t)255;
    void* p = ws + ofs;
    ofs += bytes;
    return p;
  };
  float* logq   = (float*)alloc((size_t)NTOT * KCLS * 4);
  unsigned short* fNh  = (unsigned short*)alloc((size_t)NANCH * DIM * 2);
  unsigned short* fNs  = (unsigned short*)alloc((size_t)NANCH * DIM * 2);
  unsigned short* CFhi = (unsigned short*)alloc((size_t)NTOT * DIM * 2);
  unsigned short* CFlo = (unsigned short*)alloc((size_t)NTOT * DIM * 2);
  unsigned short* cchi = (unsigned short*)alloc((size_t)KCLS * DIM * 2);
  unsigned short* cclo = (unsigned short*)alloc((size_t)KCLS * DIM * 2);
  unsigned short* xch  = (unsigned short*)alloc((size_t)NXC * DIM * 2);
  // contiguous zero region: S2 | S | cnt | cs0 | cs1 | cs2
  float* S2     = (float*)alloc((2 * NANCH + KCLS + 3 * KCLS) * 4);
  float* S      = S2 + NANCH;
  int*   cnt    = (int*)(S2 + 2 * NANCH);
  float* cs0    = S2 + 2 * NANCH + KCLS;
  float* cs1    = cs0 + KCLS;
  float* cs2    = cs1 + KCLS;
  float* Sp     = (float*)alloc(NANCH * 4);
  float* S2p    = (float*)alloc(NANCH * 4);
  float* num2A  = (float*)alloc(NANCH * 4);
  float* mlppA  = (float*)alloc(NANCH * 4);
  float* validA = (float*)alloc(NANCH * 4);
  int* labels   = (int*)alloc(NANCH * 4);
  int* sorted   = (int*)alloc(NANCH * 4);
  int* offs     = (int*)alloc(KCLS * 4);
  int* offw     = (int*)alloc(KCLS * 4);

  Idx40 idx;
  compute_idx(idx.v);

  hipMemsetAsync(S2, 0, (2 * NANCH + 4 * KCLS) * 4, stream);
  norm_copy_k<<<(2 * NANCH + NQ + KCLS + NXC) / 4, 256, 0, stream>>>(
      feats, off, pq, cc, fNh, CFhi, CFlo, cchi, cclo, xch, idx);
  rowsums2_k<<<dim3(64, 14), 256, 0, stream>>>(fNh, xch, S, S2);
  gemm_logq_mfma_k<<<NTOT / 128, 256, 0, stream>>>(CFhi, CFlo, cchi, cclo, logq);
  rowcol_k<<<NTOT / 16, 256, 0, stream>>>(logq, cs0, cs0, 0);
  rowcol_k<<<NTOT / 16, 256, 0, stream>>>(logq, cs0, cs1, 1);
  rowcol_k<<<NTOT / 16, 256, 0, stream>>>(logq, cs1, cs2, 1);
  argmax_k<<<NANCH / 256, 256, 0, stream>>>(logq, cs2, labels, cnt);
  scan_k<<<1, 64, 0, stream>>>(cnt, offs, offw);
  scatter_k<<<NANCH / 256, 256, 0, stream>>>(labels, offw, sorted, S, S2, Sp, S2p);
  sortrows_k<<<NANCH / 4, 256, 0, stream>>>(fNh, sorted, fNs);
  classpair_k<<<dim3(KCLS, 8), 64, 0, stream>>>(fNs, xch, offs, cnt, Sp, S2p,
                                                num2A, mlppA, validA);
  finalize_k<<<1, 256, 0, stream>>>(num2A, mlppA, validA, out);
}

// Round 13
// 238.731 us; speedup vs baseline: 1.0988x; 1.0932x over previous
//
#include <hip/hip_runtime.h>
#include <stdint.h>
#include <algorithm>

#define DIM   384
#define KCLS  64
#define NPIX  50
#define KSAMP 40
#define NANCH 8192      // BS*N
#define NQ    3200      // K*PIXEL_SIZE
#define NTOT  11392     // NANCH + NQ
#define NXC   2560      // K*KSAMP
// TEMP=0.1 -> 1/TEMP=10 ; TEMP/BASE_TEMP = 0.05 ; LAMB = 25

typedef __attribute__((ext_vector_type(8)))  short s16x8;
typedef __attribute__((ext_vector_type(16))) float f32x16;

struct Idx40 { int v[KSAMP]; };

__device__ __forceinline__ float wave_sum64(float v){
  #pragma unroll
  for (int o = 32; o >= 1; o >>= 1) v += __shfl_xor(v, o);
  return v;
}

__device__ __forceinline__ unsigned short f2bf(float x){
  union { float f; uint32_t u; } c; c.f = x;
  uint32_t r = c.u + 0x7FFFu + ((c.u >> 16) & 1u);   // RNE
  if ((c.u & 0x7F800000u) == 0x7F800000u) r = c.u;   // inf/nan passthrough
  return (unsigned short)(r >> 16);
}

__device__ __forceinline__ float bf2f(unsigned short h){
  union { uint32_t u; float f; } c; c.u = ((uint32_t)h) << 16;
  return c.f;
}

__device__ __forceinline__ void split_hl(float x, unsigned short& hi, unsigned short& lo){
  hi = f2bf(x);
  lo = f2bf(x - bf2f(hi));
}

// async global->LDS, 16B per lane; lds base must be wave-uniform
__device__ __forceinline__ void gload16(const unsigned short* g, unsigned short* l){
  __builtin_amdgcn_global_load_lds(
      (const __attribute__((address_space(1))) unsigned int*)g,
      (__attribute__((address_space(3))) unsigned int*)l, 16, 0, 0);
}

// ---- fused prep: normalize feats->fNh; off/pq -> CFhi/lo; cc -> cchi/lo; xc gather ----
__global__ __launch_bounds__(256) void norm_copy_k(const float* __restrict__ feats,
    const float* __restrict__ off, const float* __restrict__ pq,
    const float* __restrict__ CC,
    unsigned short* __restrict__ fNh,
    unsigned short* __restrict__ CFhi, unsigned short* __restrict__ CFlo,
    unsigned short* __restrict__ cchi, unsigned short* __restrict__ cclo,
    unsigned short* __restrict__ xch, Idx40 idx){
  int row  = blockIdx.x * 4 + (threadIdx.x >> 6);
  int lane = threadIdx.x & 63;
  if (row < 2 * NANCH){
    const float* src = (row < NANCH) ? feats + (size_t)row * DIM
                                     : off + (size_t)(row - NANCH) * DIM;
    float v[6]; float ss = 0.f;
    #pragma unroll
    for (int e = 0; e < 6; e++){ v[e] = src[lane + 64 * e]; ss += v[e] * v[e]; }
    ss = wave_sum64(ss);
    float inv = 1.f / fmaxf(sqrtf(ss), 1e-12f);
    if (row < NANCH){
      unsigned short* dh = fNh + (size_t)row * DIM;
      #pragma unroll
      for (int e = 0; e < 6; e++) dh[lane + 64 * e] = f2bf(v[e] * inv);
    } else {
      size_t base = (size_t)(row - NANCH) * DIM;
      #pragma unroll
      for (int e = 0; e < 6; e++){
        unsigned short h, l;
        split_hl(v[e] * inv, h, l);
        CFhi[base + lane + 64 * e] = h;
        CFlo[base + lane + 64 * e] = l;
      }
    }
  } else if (row < 2 * NANCH + NQ){
    int q = row - 2 * NANCH;
    const float* src = pq + (size_t)q * DIM;
    size_t base = (size_t)(NANCH + q) * DIM;
    #pragma unroll
    for (int e = 0; e < 6; e++){
      unsigned short h, l;
      split_hl(src[lane + 64 * e], h, l);
      CFhi[base + lane + 64 * e] = h;
      CFlo[base + lane + 64 * e] = l;
    }
  } else if (row < 2 * NANCH + NQ + KCLS){
    int r = row - 2 * NANCH - NQ;
    size_t base = (size_t)r * DIM;
    #pragma unroll
    for (int e = 0; e < 6; e++){
      unsigned short h, l;
      split_hl(CC[base + lane + 64 * e], h, l);
      cchi[base + lane + 64 * e] = h;
      cclo[base + lane + 64 * e] = l;
    }
  } else {
    int q = row - 2 * NANCH - NQ - KCLS;      // < NXC
    int c = q / KSAMP, t = q - c * KSAMP;
    const float* src = pq + ((size_t)c * NPIX + idx.v[t]) * DIM;
    unsigned short* dst = xch + (size_t)q * DIM;
    #pragma unroll
    for (int e = 0; e < 6; e++) dst[lane + 64 * e] = f2bf(src[lane + 64 * e]);
  }
}

// ---- logq = 25 * CF @ CC^T via hi/lo bf16 MFMA (fp32-accurate) ----
__global__ __launch_bounds__(256) void gemm_logq_mfma_k(
    const unsigned short* __restrict__ Ahi, const unsigned short* __restrict__ Alo,
    const unsigned short* __restrict__ Bhi, const unsigned short* __restrict__ Blo,
    float* __restrict__ logq){
  __shared__ unsigned short lAh[128 * 64], lAl[128 * 64];  // 16 KB each
  __shared__ unsigned short lBh[64 * 64],  lBl[64 * 64];   // 8 KB each
  int t = threadIdx.x;
  int lane = t & 63, w = t >> 6;
  int l31 = lane & 31, half = lane >> 5;
  int i0 = blockIdx.x * 128;

  int rA = w * 32 + l31;
  int swA = ((rA & 7) << 4);
  int rB0 = l31, rB1 = 32 + l31;
  int swB = ((l31 & 7) << 4);

  f32x16 acc0, acc1;
  #pragma unroll
  for (int r = 0; r < 16; r++){ acc0[r] = 0.f; acc1[r] = 0.f; }

  for (int kc = 0; kc < 6; kc++){
    __syncthreads();
    #pragma unroll
    for (int p = 0; p < 4; p++){
      int c = t + p * 256;
      int row = c >> 3, col = c & 7;
      int sw = ((col << 4) ^ ((row & 7) << 4));
      *(s16x8*)((char*)lAh + row * 128 + sw) =
          *(const s16x8*)(Ahi + (size_t)(i0 + row) * DIM + kc * 64 + col * 8);
      *(s16x8*)((char*)lAl + row * 128 + sw) =
          *(const s16x8*)(Alo + (size_t)(i0 + row) * DIM + kc * 64 + col * 8);
    }
    #pragma unroll
    for (int p = 0; p < 2; p++){
      int c = t + p * 256;
      int row = c >> 3, col = c & 7;
      int sw = ((col << 4) ^ ((row & 7) << 4));
      *(s16x8*)((char*)lBh + row * 128 + sw) =
          *(const s16x8*)(Bhi + (size_t)row * DIM + kc * 64 + col * 8);
      *(s16x8*)((char*)lBl + row * 128 + sw) =
          *(const s16x8*)(Blo + (size_t)row * DIM + kc * 64 + col * 8);
    }
    __syncthreads();
    #pragma unroll
    for (int kk = 0; kk < 4; kk++){
      int kb = kk * 32 + half * 16;
      s16x8 fah  = *(const s16x8*)((char*)lAh + rA * 128 + (kb ^ swA));
      s16x8 fal  = *(const s16x8*)((char*)lAl + rA * 128 + (kb ^ swA));
      s16x8 fb0h = *(const s16x8*)((char*)lBh + rB0 * 128 + (kb ^ swB));
      s16x8 fb0l = *(const s16x8*)((char*)lBl + rB0 * 128 + (kb ^ swB));
      s16x8 fb1h = *(const s16x8*)((char*)lBh + rB1 * 128 + (kb ^ swB));
      s16x8 fb1l = *(const s16x8*)((char*)lBl + rB1 * 128 + (kb ^ swB));
      acc0 = __builtin_amdgcn_mfma_f32_32x32x16_bf16(fah, fb0h, acc0, 0, 0, 0);
      acc0 = __builtin_amdgcn_mfma_f32_32x32x16_bf16(fah, fb0l, acc0, 0, 0, 0);
      acc0 = __builtin_amdgcn_mfma_f32_32x32x16_bf16(fal, fb0h, acc0, 0, 0, 0);
      acc1 = __builtin_amdgcn_mfma_f32_32x32x16_bf16(fah, fb1h, acc1, 0, 0, 0);
      acc1 = __builtin_amdgcn_mfma_f32_32x32x16_bf16(fah, fb1l, acc1, 0, 0, 0);
      acc1 = __builtin_amdgcn_mfma_f32_32x32x16_bf16(fal, fb1h, acc1, 0, 0, 0);
    }
  }
  #pragma unroll
  for (int r = 0; r < 16; r++){
    int rowp = (r & 3) + 8 * (r >> 2) + 4 * half;
    size_t row = (size_t)(i0 + w * 32 + rowp);
    logq[row * KCLS + l31]      = 25.f * acc0[r];
    logq[row * KCLS + 32 + l31] = 25.f * acc1[r];
  }
}

// ---- Sinkhorn row pass: optional col-normalize via -log(colsum), then rowLSE ----
__global__ __launch_bounds__(256) void rowpass_k(float* __restrict__ logq,
    const float* __restrict__ colsum, int useCol){
  int row  = blockIdx.x * 4 + (threadIdx.x >> 6);
  int lane = threadIdx.x & 63;                  // lane == column (KCLS==64)
  float v = logq[(size_t)row * KCLS + lane];
  if (useCol) v -= logf(colsum[lane]);
  float m = v;
  #pragma unroll
  for (int o = 32; o >= 1; o >>= 1) m = fmaxf(m, __shfl_xor(m, o));
  float s = expf(v - m);
  s = wave_sum64(s);
  logq[(size_t)row * KCLS + lane] = v - (m + logf(s));
}

// ---- Sinkhorn col pass: colsum[j] += sum_i exp(logq[i][j]) ----
__global__ __launch_bounds__(256) void colsum_k(const float* __restrict__ logq,
    float* __restrict__ cs){
  int r0 = blockIdx.x * 128;                    // NTOT = 89 * 128
  int t = threadIdx.x, lane = t & 63, grp = t >> 6;
  float acc = 0.f;
  for (int r = grp; r < 128; r += 4)
    acc += __expf(logq[(size_t)(r0 + r) * KCLS + lane]);
  __shared__ float red[4][64];
  red[grp][lane] = acc;
  __syncthreads();
  if (t < 64) atomicAdd(&cs[t], red[0][t] + red[1][t] + red[2][t] + red[3][t]);
}

// ---- labels = argmax (+ class histogram fused) ----
__global__ __launch_bounds__(256) void argmax_k(const float* __restrict__ logq,
    const float* __restrict__ cs, int* __restrict__ labels, int* __restrict__ cnt){
  __shared__ float clog[KCLS];
  int t = threadIdx.x;
  if (t < KCLS) clog[t] = logf(cs[t]);
  __syncthreads();
  int i = blockIdx.x * 256 + t;
  if (i >= NANCH) return;
  float best = -INFINITY; int bj = 0;
  for (int j = 0; j < KCLS; j++){
    float v = logq[(size_t)i * KCLS + j] - clog[j];
    if (v > best){ best = v; bj = j; }
  }
  labels[i] = bj;
  atomicAdd(&cnt[bj], 1);
}

__global__ void scan_k(const int* cnt, int* offs, int* offw){
  if (threadIdx.x == 0){
    int acc = 0;
    for (int c = 0; c < KCLS; c++){ offs[c] = acc; offw[c] = acc; acc += cnt[c]; }
  }
}

// ---- scatter + permute S,S2 into class-sorted position order ----
__global__ __launch_bounds__(256) void scatter_k(const int* __restrict__ labels,
    int* offw, int* __restrict__ sorted, const float* __restrict__ S,
    const float* __restrict__ S2, float* __restrict__ Sp, float* __restrict__ S2p){
  int i = blockIdx.x * 256 + threadIdx.x;
  if (i >= NANCH) return;
  int p = atomicAdd(&offw[labels[i]], 1);
  sorted[p] = i;
  Sp[p]  = S[i];
  S2p[p] = S2[i];
}

// ---- fNs[p] = fNh[sorted[p]] : class-contiguous feature rows ----
__global__ __launch_bounds__(256) void sortrows_k(const unsigned short* __restrict__ fNh,
    const int* __restrict__ sorted, unsigned short* __restrict__ fNs){
  int p = blockIdx.x * 4 + (threadIdx.x >> 6);     // 4 rows/block
  int lane = threadIdx.x & 63;
  int src = sorted[p];
  const uint32_t* s = (const uint32_t*)(fNh + (size_t)src * DIM);
  uint32_t* d = (uint32_t*)(fNs + (size_t)p * DIM);
  #pragma unroll
  for (int e = 0; e < 3; e++) d[lane + 64 * e] = s[lane + 64 * e];
}

// ---- MFMA row-sums: CYCLIC-balanced triangle, double-buffered (R10, frozen) ----
// Unordered self pair {i,j} <-> (bi, (bi+d)%64), d in [0,32]; d=32 only bi<32.
// grid.y<8: self chunk d0=4y, njt=4 (wrap mod 64). grid.y==8: d=32 singleton
// (bi<32, else exit). grid.y in [9,14): xc chunks of 4 (dst=S2, rows only).
// Off-diagonal self tiles also emit column-sums into S[j-range].
__global__ __launch_bounds__(256) void rowsums2_k(
    const unsigned short* __restrict__ A, const unsigned short* __restrict__ Bxc,
    float* __restrict__ S, float* __restrict__ S2){
  int bi = blockIdx.x, y = blockIdx.y;
  const unsigned short* Bp; float* dst;
  int d0 = 0, bjx0 = 0, njt; bool selfpart;
  if (y < 8){
    selfpart = true; Bp = A; dst = S; d0 = y * 4; njt = 4;
  } else if (y == 8){
    if (bi >= 32) return;
    selfpart = true; Bp = A; dst = S; d0 = 32; njt = 1;
  } else {
    selfpart = false; Bp = Bxc; dst = S2; bjx0 = (y - 9) * 4; njt = 4;
  }

  __shared__ unsigned short lds[2][2][128 * 64];   // [buf][A|B], 64 KB total
  int t = threadIdx.x, lane = t & 63, w = t >> 6;
  int wr = w >> 1, wc = w & 1;
  int l31 = lane & 31, half = lane >> 5;
  int i0 = bi * 128;
  int lrow = lane >> 3, srcslot = (lane & 7) ^ lrow;
  size_t loff = (size_t)lrow * DIM + srcslot * 8;   // per-lane swizzled source offset

  int rA0 = wr * 64 + l31, rA1 = rA0 + 32;
  int rB0 = wc * 64 + l31, rB1 = rB0 + 32;
  int swA = ((rA0 & 7) << 4), swB = ((rB0 & 7) << 4);

  // j column-tile (in rows of Bp) for tile index jt
  auto jcol = [&](int jt) -> int {
    if (selfpart){ int js = bi + d0 + jt; return (js & 63) * 128; }
    return (bjx0 + jt) * 128;
  };

  f32x16 s0, s1, a00, a01, a10, a11;
  #pragma unroll
  for (int r = 0; r < 16; r++){ s0[r] = 0.f; s1[r] = 0.f; }

  // prologue: stage (jt=0, kc=0) into buf 0
  {
    int j0 = jcol(0);
    #pragma unroll
    for (int c = 0; c < 4; c++){
      int chunk = w * 4 + c;
      gload16(A  + (size_t)(i0 + chunk * 8) * DIM + loff, &lds[0][0][chunk * 512]);
      gload16(Bp + (size_t)(j0 + chunk * 8) * DIM + loff, &lds[0][1][chunk * 512]);
    }
  }
  __syncthreads();

  int total = njt * 6;
  int buf = 0;
  for (int s = 0; s < total; s++){
    int jt = s / 6, kc = s - jt * 6;
    if (s + 1 < total){
      int sn = s + 1;
      int jt1 = sn / 6, kc1 = sn - jt1 * 6;
      int j1 = jcol(jt1);
      int nb = buf ^ 1;
      #pragma unroll
      for (int c = 0; c < 4; c++){
        int chunk = w * 4 + c;
        gload16(A  + (size_t)(i0 + chunk * 8) * DIM + kc1 * 64 + loff, &lds[nb][0][chunk * 512]);
        gload16(Bp + (size_t)(j1 + chunk * 8) * DIM + kc1 * 64 + loff, &lds[nb][1][chunk * 512]);
      }
    }
    if (kc == 0){
      #pragma unroll
      for (int r = 0; r < 16; r++){ a00[r] = 0.f; a01[r] = 0.f; a10[r] = 0.f; a11[r] = 0.f; }
    }
    const char* bA = (const char*)&lds[buf][0][0];
    const char* bB = (const char*)&lds[buf][1][0];
    #pragma unroll
    for (int kk = 0; kk < 4; kk++){
      int kb = kk * 32 + half * 16;
      s16x8 fa0 = *(const s16x8*)(bA + rA0 * 128 + (kb ^ swA));
      s16x8 fa1 = *(const s16x8*)(bA + rA1 * 128 + (kb ^ swA));
      s16x8 fb0 = *(const s16x8*)(bB + rB0 * 128 + (kb ^ swB));
      s16x8 fb1 = *(const s16x8*)(bB + rB1 * 128 + (kb ^ swB));
      a00 = __builtin_amdgcn_mfma_f32_32x32x16_bf16(fa0, fb0, a00, 0, 0, 0);
      a01 = __builtin_amdgcn_mfma_f32_32x32x16_bf16(fa0, fb1, a01, 0, 0, 0);
      a10 = __builtin_amdgcn_mfma_f32_32x32x16_bf16(fa1, fb0, a10, 0, 0, 0);
      a11 = __builtin_amdgcn_mfma_f32_32x32x16_bf16(fa1, fb1, a11, 0, 0, 0);
    }
    if (kc == 5){
      int j0 = jcol(jt);
      bool docol = selfpart && (d0 + jt != 0);
      float c0 = 0.f, c1 = 0.f;
      #pragma unroll
      for (int r = 0; r < 16; r++){
        float e00 = __expf(fmaf(a00[r], 10.f, -10.f));
        float e01 = __expf(fmaf(a01[r], 10.f, -10.f));
        float e10 = __expf(fmaf(a10[r], 10.f, -10.f));
        float e11 = __expf(fmaf(a11[r], 10.f, -10.f));
        s0[r] += e00 + e01;
        s1[r] += e10 + e11;
        c0 += e00 + e10;     // column wc*64 + l31
        c1 += e01 + e11;     // column wc*64 + 32 + l31
      }
      if (docol){
        c0 += __shfl_xor(c0, 32);
        c1 += __shfl_xor(c1, 32);
        if (half == 0){
          atomicAdd(&dst[j0 + wc * 64 + l31], c0);
          atomicAdd(&dst[j0 + wc * 64 + 32 + l31], c1);
        }
      }
    }
    __syncthreads();    // drains vmcnt(0): next buffer ready; all waves done reading buf
    buf ^= 1;
  }

  #pragma unroll
  for (int o = 1; o < 32; o <<= 1){
    #pragma unroll
    for (int r = 0; r < 16; r++){
      s0[r] += __shfl_xor(s0[r], o);
      s1[r] += __shfl_xor(s1[r], o);
    }
  }
  if (l31 == 0){
    #pragma unroll
    for (int r = 0; r < 16; r++){
      int rowp = (r & 3) + 8 * (r >> 2) + 4 * half;
      atomicAdd(&dst[i0 + wr * 64 + rowp], s0[r]);
      atomicAdd(&dst[i0 + wr * 64 + 32 + rowp], s1[r]);
    }
  }
}

// ---- per-class positive numerators, class-sorted rows, position-indexed outputs ----
__device__ __forceinline__ void gram2(const s16x8* afr,
    const unsigned short* b0, const unsigned short* b1, f32x16& acc0, f32x16& acc1){
  #pragma unroll
  for (int ks = 0; ks < 24; ks++){
    s16x8 v0 = *(const s16x8*)(b0 + ks * 16);
    s16x8 v1 = *(const s16x8*)(b1 + ks * 16);
    acc0 = __builtin_amdgcn_mfma_f32_32x32x16_bf16(afr[ks], v0, acc0, 0, 0, 0);
    acc1 = __builtin_amdgcn_mfma_f32_32x32x16_bf16(afr[ks], v1, acc1, 0, 0, 0);
  }
}

__global__ __launch_bounds__(64) void classpair_k(
    const unsigned short* __restrict__ fNs, const unsigned short* __restrict__ xch,
    const int* __restrict__ offs, const int* __restrict__ cnt,
    const float* __restrict__ S, const float* __restrict__ S2,
    float* __restrict__ num2A, float* __restrict__ mlppA, float* __restrict__ validA){
  int c = blockIdx.x;
  int n = cnt[c], o0 = offs[c];
  if (n == 0) return;
  int lane = threadIdx.x;
  int l31 = lane & 31, half = lane >> 5;
  int ntiles = (n + 31) >> 5;

  for (int rt = blockIdx.y; rt < ntiles; rt += gridDim.y){
    int rpos = rt * 32 + l31;
    const unsigned short* arow = fNs + (size_t)(o0 + (rpos < n ? rpos : 0)) * DIM + half * 8;
    s16x8 afr[24];
    #pragma unroll
    for (int ks = 0; ks < 24; ks++) afr[ks] = *(const s16x8*)(arow + ks * 16);

    // ===== ppc2 =====
    f32x16 p20, p21;
    #pragma unroll
    for (int r = 0; r < 16; r++){ p20[r] = 0.f; p21[r] = 0.f; }
    {
      int c1 = 32 + l31;
      const unsigned short* b0 = xch + ((size_t)c * KSAMP + l31) * DIM + half * 8;
      const unsigned short* b1 = xch + ((size_t)c * KSAMP + (c1 < KSAMP ? c1 : 0)) * DIM + half * 8;
      gram2(afr, b0, b1, p20, p21);
    }
    f32x16 red;
    #pragma unroll
    for (int r = 0; r < 16; r++){
      float v0 = expf(fmaf(p20[r], 10.f, -10.f));
      float v1 = (l31 < 8) ? expf(fmaf(p21[r], 10.f, -10.f)) : 0.f;
      red[r] = v0 + v1;
    }
    #pragma unroll
    for (int o = 1; o < 32; o <<= 1)
      #pragma unroll
      for (int r = 0; r < 16; r++) red[r] += __shfl_xor(red[r], o);
    float neg2[16];
    #pragma unroll
    for (int r = 0; r < 16; r++){
      int rowp = (r & 3) + 8 * (r >> 2) + 4 * half;
      int rp = rt * 32 + rowp;
      neg2[r] = (rp < n) ? S2[o0 + rp] - red[r] : 1.f;
    }
    #pragma unroll
    for (int r = 0; r < 16; r++){
      float l0 = fmaf(p20[r], 10.f, -10.f);
      float l1 = fmaf(p21[r], 10.f, -10.f);
      float a = l0 - logf(expf(l0) + neg2[r]);
      float b = (l31 < 8) ? l1 - logf(expf(l1) + neg2[r]) : 0.f;
      red[r] = a + b;
    }
    #pragma unroll
    for (int o = 1; o < 32; o <<= 1)
      #pragma unroll
      for (int r = 0; r < 16; r++) red[r] += __shfl_xor(red[r], o);
    if (l31 == 0){
      #pragma unroll
      for (int r = 0; r < 16; r++){
        int rowp = (r & 3) + 8 * (r >> 2) + 4 * half;
        int rp = rt * 32 + rowp;
        if (rp < n) num2A[o0 + rp] = red[r];
      }
    }

    // ===== ppc =====
    f32x16 pe;
    #pragma unroll
    for (int r = 0; r < 16; r++) pe[r] = 0.f;
    for (int ct = 0; ct < ntiles; ct += 2){
      int cp0 = ct * 32 + l31;
      int cp1 = (ct + 1) * 32 + l31;
      bool has1 = (ct + 1) < ntiles;
      const unsigned short* b0 = fNs + (size_t)(o0 + (cp0 < n ? cp0 : 0)) * DIM + half * 8;
      const unsigned short* b1 = fNs + (size_t)(o0 + (has1 && cp1 < n ? cp1 : 0)) * DIM + half * 8;
      f32x16 a0, a1;
      #pragma unroll
      for (int r = 0; r < 16; r++){ a0[r] = 0.f; a1[r] = 0.f; }
      gram2(afr, b0, b1, a0, a1);
      #pragma unroll
      for (int r = 0; r < 16; r++){
        int rowp = (r & 3) + 8 * (r >> 2) + 4 * half;
        int rp = rt * 32 + rowp;
        if (cp0 < n && cp0 != rp) pe[r] += expf(fmaf(a0[r], 10.f, -10.f));
        if (has1 && cp1 < n && cp1 != rp) pe[r] += expf(fmaf(a1[r], 10.f, -10.f));
      }
    }
    #pragma unroll
    for (int o = 1; o < 32; o <<= 1)
      #pragma unroll
      for (int r = 0; r < 16; r++) pe[r] += __shfl_xor(pe[r], o);
    float neg[16];
    #pragma unroll
    for (int r = 0; r < 16; r++){
      int rowp = (r & 3) + 8 * (r >> 2) + 4 * half;
      int rp = rt * 32 + rowp;
      neg[r] = (rp < n) ? S[o0 + rp] - pe[r] : 1.f;
    }

    f32x16 nm;
    #pragma unroll
    for (int r = 0; r < 16; r++) nm[r] = 0.f;
    for (int ct = 0; ct < ntiles; ct += 2){
      int cp0 = ct * 32 + l31;
      int cp1 = (ct + 1) * 32 + l31;
      bool has1 = (ct + 1) < ntiles;
      const unsigned short* b0 = fNs + (size_t)(o0 + (cp0 < n ? cp0 : 0)) * DIM + half * 8;
      const unsigned short* b1 = fNs + (size_t)(o0 + (has1 && cp1 < n ? cp1 : 0)) * DIM + half * 8;
      f32x16 a0, a1;
      #pragma unroll
      for (int r = 0; r < 16; r++){ a0[r] = 0.f; a1[r] = 0.f; }
      gram2(afr, b0, b1, a0, a1);
      #pragma unroll
      for (int r = 0; r < 16; r++){
        int rowp = (r & 3) + 8 * (r >> 2) + 4 * half;
        int rp = rt * 32 + rowp;
        if (cp0 < n && cp0 != rp){
          float l = fmaf(a0[r], 10.f, -10.f);
          nm[r] += l - logf(expf(l) + neg[r]);
        }
        if (has1 && cp1 < n && cp1 != rp){
          float l = fmaf(a1[r], 10.f, -10.f);
          nm[r] += l - logf(expf(l) + neg[r]);
        }
      }
    }
    #pragma unroll
    for (int o = 1; o < 32; o <<= 1)
      #pragma unroll
      for (int r = 0; r < 16; r++) nm[r] += __shfl_xor(nm[r], o);
    if (l31 == 0){
      #pragma unroll
      for (int r = 0; r < 16; r++){
        int rowp = (r & 3) + 8 * (r >> 2) + 4 * half;
        int rp = rt * 32 + rowp;
        if (rp < n){
          if (n > 1){ mlppA[o0 + rp] = nm[r] / (float)(n - 1); validA[o0 + rp] = 1.f; }
          else      { mlppA[o0 + rp] = 0.f; validA[o0 + rp] = 0.f; }
        }
      }
    }
  }
}

__global__ __launch_bounds__(256) void finalize_k(const float* __restrict__ num2A,
    const float* __restrict__ mlppA, const float* __restrict__ validA,
    float* __restrict__ out){
  int t = threadIdx.x;
  float s2 = 0.f, sm = 0.f, sv = 0.f;
  for (int i = t; i < NANCH; i += 256){ s2 += num2A[i]; sm += mlppA[i]; sv += validA[i]; }
  __shared__ float a2[256], am[256], av[256];
  a2[t] = s2; am[t] = sm; av[t] = sv; __syncthreads();
  for (int o = 128; o >= 1; o >>= 1){
    if (t < o){ a2[t] += a2[t+o]; am[t] += am[t+o]; av[t] += av[t+o]; }
    __syncthreads();
  }
  if (t == 0){
    float loss1 = -0.05f * a2[0] / (40.f * (float)NANCH);
    float loss2 = -0.05f * am[0] / fmaxf(av[0], 1.f);
    out[0] = loss1 + loss2;
  }
}

// ---- host: replicate jax.random.permutation(key(1), 50)[:40] (threefry-2x32) ----
static void tf2x32(uint32_t k0, uint32_t k1, uint32_t x0, uint32_t x1, uint32_t out[2]){
  uint32_t ks[3] = { k0, k1, k0 ^ k1 ^ 0x1BD11BDAu };
  static const int R[2][4] = { {13,15,26,6}, {17,29,16,24} };
  x0 += ks[0]; x1 += ks[1];
  for (int i = 0; i < 5; i++){
    for (int j = 0; j < 4; j++){
      x0 += x1;
      int r = R[i & 1][j];
      x1 = (x1 << r) | (x1 >> (32 - r));
      x1 ^= x0;
    }
    x0 += ks[(i + 1) % 3];
    x1 += ks[(i + 2) % 3] + (uint32_t)(i + 1);
  }
  out[0] = x0; out[1] = x1;
}

static void compute_idx(int idx_out[KSAMP]){
  uint32_t p0[2], p1[2];
  tf2x32(0u, 1u, 0u, 2u, p0);
  tf2x32(0u, 1u, 1u, 3u, p1);
  uint32_t sk0 = p0[1], sk1 = p1[1];        // subkey = keys[1]
  uint32_t bits[NPIX];
  for (int i = 0; i < 25; i++){
    uint32_t o[2];
    tf2x32(sk0, sk1, (uint32_t)i, (uint32_t)(25 + i), o);
    bits[i] = o[0]; bits[25 + i] = o[1];
  }
  int perm[NPIX];
  for (int i = 0; i < NPIX; i++) perm[i] = i;
  std::stable_sort(perm, perm + NPIX, [&](int a, int b){ return bits[a] < bits[b]; });
  for (int i = 0; i < KSAMP; i++) idx_out[i] = perm[i];
}

extern "C" void kernel_launch(void* const* d_in, const int* in_sizes, int n_in,
                              void* d_out, int out_size, void* d_ws, size_t ws_size,
                              hipStream_t stream){
  const float* feats = (const float*)d_in[0];
  const float* off   = (const float*)d_in[1];
  const float* cc    = (const float*)d_in[2];
  const float* pq    = (const float*)d_in[3];
  float* out = (float*)d_out;

  char* ws = (char*)d_ws;
  size_t ofs = 0;
  auto alloc = [&](size_t bytes) -> void* {
    ofs = (ofs + 255) & ~(size_t)255;
    void* p = ws + ofs;
    ofs += bytes;
    return p;
  };
  float* logq   = (float*)alloc((size_t)NTOT * KCLS * 4);
  unsigned short* fNh  = (unsigned short*)alloc((size_t)NANCH * DIM * 2);
  unsigned short* fNs  = (unsigned short*)alloc((size_t)NANCH * DIM * 2);
  unsigned short* CFhi = (unsigned short*)alloc((size_t)NTOT * DIM * 2);
  unsigned short* CFlo = (unsigned short*)alloc((size_t)NTOT * DIM * 2);
  unsigned short* cchi = (unsigned short*)alloc((size_t)KCLS * DIM * 2);
  unsigned short* cclo = (unsigned short*)alloc((size_t)KCLS * DIM * 2);
  unsigned short* xch  = (unsigned short*)alloc((size_t)NXC * DIM * 2);
  // contiguous zero region: S2 | S | cnt | cs0 | cs1 | cs2
  float* S2     = (float*)alloc((2 * NANCH + KCLS + 3 * KCLS) * 4);
  float* S      = S2 + NANCH;
  int*   cnt    = (int*)(S2 + 2 * NANCH);
  float* cs0    = S2 + 2 * NANCH + KCLS;
  float* cs1    = cs0 + KCLS;
  float* cs2    = cs1 + KCLS;
  float* Sp     = (float*)alloc(NANCH * 4);
  float* S2p    = (float*)alloc(NANCH * 4);
  float* num2A  = (float*)alloc(NANCH * 4);
  float* mlppA  = (float*)alloc(NANCH * 4);
  float* validA = (float*)alloc(NANCH * 4);
  int* labels   = (int*)alloc(NANCH * 4);
  int* sorted   = (int*)alloc(NANCH * 4);
  int* offs     = (int*)alloc(KCLS * 4);
  int* offw     = (int*)alloc(KCLS * 4);

  Idx40 idx;
  compute_idx(idx.v);

  hipMemsetAsync(S2, 0, (2 * NANCH + 4 * KCLS) * 4, stream);
  norm_copy_k<<<(2 * NANCH + NQ + KCLS + NXC) / 4, 256, 0, stream>>>(
      feats, off, pq, cc, fNh, CFhi, CFlo, cchi, cclo, xch, idx);
  rowsums2_k<<<dim3(64, 14), 256, 0, stream>>>(fNh, xch, S, S2);
  gemm_logq_mfma_k<<<NTOT / 128, 256, 0, stream>>>(CFhi, CFlo, cchi, cclo, logq);
  rowpass_k<<<NTOT / 4, 256, 0, stream>>>(logq, cs0, 0);
  colsum_k<<<NTOT / 128, 256, 0, stream>>>(logq, cs0);
  rowpass_k<<<NTOT / 4, 256, 0, stream>>>(logq, cs0, 1);
  colsum_k<<<NTOT / 128, 256, 0, stream>>>(logq, cs1);
  rowpass_k<<<NTOT / 4, 256, 0, stream>>>(logq, cs1, 1);
  colsum_k<<<NTOT / 128, 256, 0, stream>>>(logq, cs2);
  argmax_k<<<NANCH / 256, 256, 0, stream>>>(logq, cs2, labels, cnt);
  scan_k<<<1, 64, 0, stream>>>(cnt, offs, offw);
  scatter_k<<<NANCH / 256, 256, 0, stream>>>(labels, offw, sorted, S, S2, Sp, S2p);
  sortrows_k<<<NANCH / 4, 256, 0, stream>>>(fNh, sorted, fNs);
  classpair_k<<<dim3(KCLS, 8), 64, 0, stream>>>(fNs, xch, offs, cnt, Sp, S2p,
                                                num2A, mlppA, validA);
  finalize_k<<<1, 256, 0, stream>>>(num2A, mlppA, validA, out);
}